// Round 1
// baseline (785.561 us; speedup 1.0000x reference)
//
#include <hip/hip_runtime.h>

typedef unsigned short u16;
typedef __attribute__((ext_vector_type(8))) short short8;
typedef __attribute__((ext_vector_type(4))) float v4f;

__device__ __forceinline__ float b2f(u16 u) {
  union { unsigned int i; float f; } v; v.i = ((unsigned int)u) << 16; return v.f;
}
__device__ __forceinline__ u16 f2b(float f) {
  unsigned int x = __float_as_uint(f);
  x += 0x7fffu + ((x >> 16) & 1u);   // RNE
  return (u16)(x >> 16);
}
// dtype-flexible input load: f32 ? fp32 array : bf16(u16) array
__device__ __forceinline__ float ldin(const void* p, size_t i, int f32) {
  return f32 ? ((const float*)p)[i] : b2f(((const u16*)p)[i]);
}

// ---------------- dtype sniff: bf16 vs fp32, from query's raw bits ----------------
__global__ void sniff_k(const void* __restrict__ q, int* __restrict__ flag) {
  __shared__ int cnt;
  if (threadIdx.x == 0) cnt = 0;
  __syncthreads();
  const u16* p = (const u16*)q;
  int w = 0;
  for (int i = threadIdx.x; i < 1024; i += 256) {
    u16 u = p[i];
    int e = (u >> 7) & 0xFF;
    if (u != 0 && u != 0x8000 && (e >= 0xC0 || e < 0x40)) w++;
  }
  atomicAdd(&cnt, w);
  __syncthreads();
  if (threadIdx.x == 0) *flag = (cnt >= 32) ? 1 : 0;   // wild bits => fp32
}

// ---------------- K-split partial 32x1024 GEMM (latency fix for K/V prep) ---------
// P[kb][s][j] = sum_{k in chunk kb} A[s][k] * W[k][j]
// grid (4 jb, 32 kb) x 256 thr.  a_f32_always=1 => A is fp32 regardless of flag.
__global__ void gemm32_part(const void* __restrict__ A, const void* __restrict__ W,
                            float* __restrict__ P, const int* __restrict__ flag,
                            int a_f32_always) {
  const int f32 = *flag;
  const int af = a_f32_always ? 1 : f32;
  const int jb = blockIdx.x;     // 0..3
  const int kb = blockIdx.y;     // 0..31
  const int tid = threadIdx.x;
  const int j = jb * 256 + tid;
  const int k0 = kb * 32;
  __shared__ float ks[32][32];   // [s][k] chunk of A
  for (int i = tid; i < 1024; i += 256) {
    int s = i >> 5, kk = i & 31;
    ks[s][kk] = ldin(A, (size_t)s * 1024 + k0 + kk, af);
  }
  __syncthreads();
  float acc[32];
#pragma unroll
  for (int s = 0; s < 32; ++s) acc[s] = 0.f;
#pragma unroll
  for (int k = 0; k < 32; ++k) {
    float w = ldin(W, (size_t)(k0 + k) * 1024 + j, f32);
#pragma unroll
    for (int s = 0; s < 32; ++s) acc[s] += ks[s][k] * w;
  }
  float* Pp = P + (size_t)kb * 32768 + j;
#pragma unroll
  for (int s = 0; s < 32; ++s) Pp[(size_t)s * 1024] = acc[s];
}

// Out[s*1024+j] = bias[j] + sum_kb P[kb][s][j]   (deterministic reduce)
__global__ void gemm32_reduce(const float* __restrict__ P, const void* __restrict__ bias,
                              float* __restrict__ Out, const int* __restrict__ flag) {
  const int f32 = *flag;
  int t = blockIdx.x * 256 + threadIdx.x;  // 32768
  int j = t & 1023;
  float acc = ldin(bias, j, f32);
#pragma unroll
  for (int kb = 0; kb < 32; ++kb) acc += P[(size_t)kb * 32768 + t];
  Out[t] = acc;
}

// ---------------- prep (fallback path only): K = key_param @ Wk + bk --------------
__global__ void kernel_K(const void* __restrict__ kp, const void* __restrict__ Wk,
                         const void* __restrict__ bk, float* __restrict__ Kf,
                         const int* __restrict__ flag) {
  const int f32 = *flag;
  int t = blockIdx.x * 256 + threadIdx.x;   // 32768 = 32 s x 1024 j
  int s = t >> 10, j = t & 1023;
  float acc = 0.f;
#pragma unroll 8
  for (int d = 0; d < 1024; ++d)
    acc += ldin(kp, (size_t)s * 1024 + d, f32) * ldin(Wk, (size_t)d * 1024 + j, f32);
  Kf[t] = acc + ldin(bk, j, f32);
}

// ---------------- prep (fallback path only): V = K @ Wv + bv ----------------
__global__ void kernel_V(const float* __restrict__ Kf, const void* __restrict__ Wv,
                         const void* __restrict__ bv, float* __restrict__ Vf,
                         const int* __restrict__ flag) {
  const int f32 = *flag;
  int t = blockIdx.x * 256 + threadIdx.x;
  int s = t >> 10, j = t & 1023;
  const float* kr = Kf + (size_t)s * 1024;
  float acc = 0.f;
#pragma unroll 8
  for (int d = 0; d < 1024; ++d) acc += kr[d] * ldin(Wv, (size_t)d * 1024 + j, f32);
  Vf[t] = acc + ldin(bv, j, f32);
}

// ---------------- prep: Mt[hs][d] = (1/8) sum_e Wq[d, h*64+e] * K[s, h*64+e] ------
__global__ void kernel_M(const float* __restrict__ Kf, const void* __restrict__ Wq,
                         const void* __restrict__ bq, u16* __restrict__ Mt,
                         float* __restrict__ bias_s, const int* __restrict__ flag) {
  const int f32 = *flag;
  int b = blockIdx.x;               // b = h*32+s = hs
  int h = b >> 5, s = b & 31, tid = threadIdx.x;
  __shared__ float ksl[64];
  if (tid < 64) ksl[tid] = Kf[(size_t)s * 1024 + h * 64 + tid] * 0.125f;  // fold 1/sqrt(64)
  __syncthreads();
#pragma unroll
  for (int r = 0; r < 4; ++r) {
    int d = tid + r * 256;
    float acc = 0.f;
#pragma unroll
    for (int e = 0; e < 64; ++e)
      acc += ldin(Wq, (size_t)d * 1024 + h * 64 + e, f32) * ksl[e];
    Mt[(size_t)b * 1024 + d] = f2b(acc);
  }
  if (tid == 0) {
    float acc = 0.f;
    for (int e = 0; e < 64; ++e) acc += ldin(bq, h * 64 + e, f32) * ksl[e];
    bias_s[b] = acc;
  }
}

// ---------------- prep: N2t[h][j][r*32+s] = sum_d V[s, h*64+d] * Wo[r*64+d, j] ----
__global__ void kernel_N2(const float* __restrict__ Vf, const void* __restrict__ Wo,
                          u16* __restrict__ N2t, const int* __restrict__ flag) {
  const int f32 = *flag;
  int blk = blockIdx.x;             // 1024 blocks: h(16) x r(16) x jb(4)
  int h = blk >> 6, r = (blk >> 2) & 15, jb = blk & 3;
  int tid = threadIdx.x;
  int j = jb * 256 + tid;
  __shared__ float vsl[2048];       // V[s=0..31][d=0..63] for this h
  for (int i = tid; i < 2048; i += 256) {
    int s = i >> 6, d = i & 63;
    vsl[i] = Vf[(size_t)s * 1024 + h * 64 + d];
  }
  __syncthreads();
  float acc[32];
#pragma unroll
  for (int s = 0; s < 32; ++s) acc[s] = 0.f;
  for (int d = 0; d < 64; ++d) {
    float w = ldin(Wo, (size_t)(r * 64 + d) * 1024 + j, f32);
#pragma unroll
    for (int s = 0; s < 32; ++s) acc[s] += vsl[s * 64 + d] * w;
  }
  union { u16 o[32]; uint4 v[4]; } ou __attribute__((aligned(16)));
#pragma unroll
  for (int s = 0; s < 32; ++s) ou.o[s] = f2b(acc[s]);
  uint4* dst = (uint4*)(N2t + ((size_t)(h * 1024 + j)) * 512 + r * 32);
#pragma unroll
  for (int i = 0; i < 4; ++i) dst[i] = ou.v[i];
}

// ---------------- prep: bo -> fp32 ----------------
__global__ void kernel_bo(const void* __restrict__ bo, float* __restrict__ bo_f,
                          const int* __restrict__ flag) {
  const int f32 = *flag;
  int i = blockIdx.x * 256 + threadIdx.x;
  if (i < 1024) bo_f[i] = ldin(bo, i, f32);
}

// ---------------- GEMM1: Z2 = query @ Mt^T + bias_s, written permuted -------------
// C[rw][col] (rw in [0,32768), col=hs in [0,512)) -> Z2[h][rw>>4][(rw&15)*32 + s]
__global__ void gemm_scores(const void* __restrict__ A, const u16* __restrict__ B,
                            const float* __restrict__ bias, u16* __restrict__ Z2,
                            const int* __restrict__ flag) {
  const int f32 = *flag;
  const int K = 1024;
  __shared__ u16 As[128 * 32] __attribute__((aligned(16)));
  __shared__ u16 Bs[128 * 32] __attribute__((aligned(16)));
  const int tid = threadIdx.x;
  const int wave = tid >> 6;
  const int lane = tid & 63;
  const int quad = lane >> 4;
  const int l16 = lane & 15;
  const int m0 = blockIdx.y * 128;
  const int n0 = blockIdx.x * 128;
  const int wm = (wave >> 1) * 64;
  const int wn = (wave & 1) * 64;

  v4f acc[4][4] = {};

  const int idx0 = tid, idx1 = 256 + tid;
  const int r0 = idx0 >> 2, c0 = (idx0 & 3) * 8;
  const int r1 = idx1 >> 2, c1 = (idx1 & 3) * 8;
  const u16* Bb = B + (size_t)n0 * K;

  for (int k0 = 0; k0 < K; k0 += 32) {
    size_t offA0 = (size_t)(m0 + r0) * K + k0 + c0;
    size_t offA1 = (size_t)(m0 + r1) * K + k0 + c1;
    if (!f32) {
      *(uint4*)&As[idx0 * 8] = *(const uint4*)((const u16*)A + offA0);
      *(uint4*)&As[idx1 * 8] = *(const uint4*)((const u16*)A + offA1);
    } else {
      const float* fA = (const float*)A;
      // 32B-aligned offsets (k0%32==0, c0%8==0) -> vector loads
      v4f a0 = *(const v4f*)(fA + offA0);
      v4f a1 = *(const v4f*)(fA + offA0 + 4);
      v4f a2 = *(const v4f*)(fA + offA1);
      v4f a3 = *(const v4f*)(fA + offA1 + 4);
      union { uint4 v; u16 w[8]; } t0 __attribute__((aligned(16)));
      union { uint4 v; u16 w[8]; } t1 __attribute__((aligned(16)));
#pragma unroll
      for (int e = 0; e < 4; ++e) { t0.w[e] = f2b(a0[e]); t0.w[e + 4] = f2b(a1[e]); }
#pragma unroll
      for (int e = 0; e < 4; ++e) { t1.w[e] = f2b(a2[e]); t1.w[e + 4] = f2b(a3[e]); }
      *(uint4*)&As[idx0 * 8] = t0.v;
      *(uint4*)&As[idx1 * 8] = t1.v;
    }
    *(uint4*)&Bs[idx0 * 8] = *(const uint4*)(Bb + (size_t)r0 * K + k0 + c0);
    *(uint4*)&Bs[idx1 * 8] = *(const uint4*)(Bb + (size_t)r1 * K + k0 + c1);
    __syncthreads();
    short8 af[4], bf[4];
#pragma unroll
    for (int i = 0; i < 4; ++i)
      af[i] = *(const short8*)&As[(wm + i * 16 + l16) * 32 + quad * 8];
#pragma unroll
    for (int i = 0; i < 4; ++i)
      bf[i] = *(const short8*)&Bs[(wn + i * 16 + l16) * 32 + quad * 8];
#pragma unroll
    for (int mi = 0; mi < 4; ++mi)
#pragma unroll
      for (int ni = 0; ni < 4; ++ni)
        acc[mi][ni] = __builtin_amdgcn_mfma_f32_16x16x32_bf16(af[mi], bf[ni], acc[mi][ni], 0, 0, 0);
    __syncthreads();
  }

#pragma unroll
  for (int ni = 0; ni < 4; ++ni) {
    const int col = n0 + wn + ni * 16 + l16;
    const float bcol = bias[col];
    const int h = col >> 5, s = col & 31;
#pragma unroll
    for (int mi = 0; mi < 4; ++mi) {
      const int rbase = m0 + wm + mi * 16 + quad * 4;
#pragma unroll
      for (int rr = 0; rr < 4; ++rr) {
        const int rw = rbase + rr;
        const size_t addr = (size_t)h * 1048576 + (size_t)(rw >> 4) * 512 + (rw & 15) * 32 + s;
        Z2[addr] = f2b(acc[mi][ni][rr] + bcol);
      }
    }
  }
}

// ---------------- sparsemax over groups of 32, in place on Z2 (bf16) --------------
__global__ void sparsemax_k(u16* __restrict__ Z) {
  int t = blockIdx.x * 256 + threadIdx.x;   // 524288 groups of 32
  u16* zp = Z + (size_t)t * 32;
  union { uint4 v[4]; u16 w[32]; } raw __attribute__((aligned(16)));
  const uint4* rp4 = (const uint4*)zp;
#pragma unroll
  for (int i = 0; i < 4; ++i) raw.v[i] = rp4[i];
  float z[32], zs[32];
#pragma unroll
  for (int i = 0; i < 32; ++i) { z[i] = b2f(raw.w[i]); zs[i] = z[i]; }
#pragma unroll
  for (int kk = 2; kk <= 32; kk <<= 1) {
#pragma unroll
    for (int j = kk >> 1; j > 0; j >>= 1) {
#pragma unroll
      for (int i = 0; i < 32; ++i) {
        int ij = i ^ j;
        if (ij > i) {
          bool up = ((i & kk) == 0);
          float a = zs[i], b = zs[ij];
          float hi = fmaxf(a, b), lo = fminf(a, b);
          zs[i]  = up ? hi : lo;
          zs[ij] = up ? lo : hi;
        }
      }
    }
  }
  float cum = 0.f, cumsel = 0.f;
  int ksup = 1;
#pragma unroll
  for (int i = 0; i < 32; ++i) {
    cum += zs[i];
    if (1.f + (float)(i + 1) * zs[i] > cum) { ksup = i + 1; cumsel = cum; }
  }
  float tau = (cumsel - 1.f) / (float)ksup;
  union { u16 o[32]; uint4 v[4]; } ou __attribute__((aligned(16)));
#pragma unroll
  for (int i = 0; i < 32; ++i) ou.o[i] = f2b(fmaxf(z[i] - tau, 0.f));
  uint4* op = (uint4*)zp;
#pragma unroll
  for (int i = 0; i < 4; ++i) op[i] = ou.v[i];
}

// ---------------- GEMM2 (batched over h): out_h = A_sp_h @ N2t_h^T + bo -----------
__global__ void gemm_out(const u16* __restrict__ Z2, const u16* __restrict__ N2t,
                         const float* __restrict__ bias, void* __restrict__ out,
                         const int* __restrict__ flag) {
  const int f32 = *flag;
  const int K = 512;
  const int h = blockIdx.z;
  __shared__ u16 As[128 * 32] __attribute__((aligned(16)));
  __shared__ u16 Bs[128 * 32] __attribute__((aligned(16)));
  const int tid = threadIdx.x;
  const int wave = tid >> 6;
  const int lane = tid & 63;
  const int quad = lane >> 4;
  const int l16 = lane & 15;
  const int m0 = blockIdx.y * 128;
  const int n0 = blockIdx.x * 128;
  const int wm = (wave >> 1) * 64;
  const int wn = (wave & 1) * 64;

  v4f acc[4][4] = {};

  const u16* Ab = Z2 + (size_t)h * 2048 * 512 + (size_t)m0 * K;
  const u16* Bb = N2t + (size_t)h * 1024 * 512 + (size_t)n0 * K;
  const int idx0 = tid, idx1 = 256 + tid;
  const int r0 = idx0 >> 2, c0 = (idx0 & 3) * 8;
  const int r1 = idx1 >> 2, c1 = (idx1 & 3) * 8;

  for (int k0 = 0; k0 < K; k0 += 32) {
    *(uint4*)&As[idx0 * 8] = *(const uint4*)(Ab + (size_t)r0 * K + k0 + c0);
    *(uint4*)&As[idx1 * 8] = *(const uint4*)(Ab + (size_t)r1 * K + k0 + c1);
    *(uint4*)&Bs[idx0 * 8] = *(const uint4*)(Bb + (size_t)r0 * K + k0 + c0);
    *(uint4*)&Bs[idx1 * 8] = *(const uint4*)(Bb + (size_t)r1 * K + k0 + c1);
    __syncthreads();
    short8 af[4], bf[4];
#pragma unroll
    for (int i = 0; i < 4; ++i)
      af[i] = *(const short8*)&As[(wm + i * 16 + l16) * 32 + quad * 8];
#pragma unroll
    for (int i = 0; i < 4; ++i)
      bf[i] = *(const short8*)&Bs[(wn + i * 16 + l16) * 32 + quad * 8];
#pragma unroll
    for (int mi = 0; mi < 4; ++mi)
#pragma unroll
      for (int ni = 0; ni < 4; ++ni)
        acc[mi][ni] = __builtin_amdgcn_mfma_f32_16x16x32_bf16(af[mi], bf[ni], acc[mi][ni], 0, 0, 0);
    __syncthreads();
  }

  float bv4[4];
#pragma unroll
  for (int ni = 0; ni < 4; ++ni) bv4[ni] = bias[n0 + wn + ni * 16 + l16];
#pragma unroll
  for (int mi = 0; mi < 4; ++mi) {
    const int rl = m0 + wm + mi * 16 + quad * 4;
#pragma unroll
    for (int rr = 0; rr < 4; ++rr) {
      const int rlr = rl + rr;
      const int orow = (rlr >> 8) * 4096 + h * 256 + (rlr & 255);
#pragma unroll
      for (int ni = 0; ni < 4; ++ni) {
        const int col = n0 + wn + ni * 16 + l16;
        const float v = acc[mi][ni][rr] + bv4[ni];
        const size_t oi = (size_t)orow * 1024 + col;
        if (f32) ((float*)out)[oi] = v;
        else     ((u16*)out)[oi] = f2b(v);
      }
    }
  }
}

// ---------------- ws-light fused fallback ----------------
__global__ void __launch_bounds__(256) fused_fallback(
    const void* __restrict__ query, const u16* __restrict__ Mt,
    const float* __restrict__ bias_s, const u16* __restrict__ N2t,
    const float* __restrict__ bo_f, void* __restrict__ out,
    const int* __restrict__ flag) {
  const int f32 = *flag;
  __shared__ float sc[256 * 32];
  __shared__ u16 qch[256 * 72];
  __shared__ u16 mh[32 * 64];
  const int t = threadIdx.x;
  const int bb = blockIdx.x;              // 128 blocks: b(8) x atile(16)
  const int b = bb >> 4, atile = bb & 15;
  const int l0 = atile * 256;
  const size_t qbase = ((size_t)b * 4096 + l0) * 1024;

  for (int h = 0; h < 16; ++h) {
    float acc32[32];
#pragma unroll
    for (int s = 0; s < 32; ++s) acc32[s] = bias_s[h * 32 + s];
    for (int d0 = 0; d0 < 1024; d0 += 64) {
      __syncthreads();
#pragma unroll
      for (int i = 0; i < 8; ++i) {
        int f4 = t + i * 256;
        int row = f4 >> 3, c8 = f4 & 7;
        size_t off = qbase + (size_t)row * 1024 + d0 + c8 * 8;
        if (!f32) {
          *(uint4*)&qch[row * 72 + c8 * 8] = *(const uint4*)((const u16*)query + off);
        } else {
          union { uint4 v; u16 w[8]; } tq __attribute__((aligned(16)));
#pragma unroll
          for (int e = 0; e < 8; ++e) tq.w[e] = f2b(((const float*)query)[off + e]);
          *(uint4*)&qch[row * 72 + c8 * 8] = tq.v;
        }
      }
      { int row = t >> 3, c8 = t & 7;
        *(uint4*)&mh[row * 64 + c8 * 8] =
            *(const uint4*)(Mt + (size_t)(h * 32 + row) * 1024 + d0 + c8 * 8); }
      __syncthreads();
      float qrow[64];
#pragma unroll
      for (int c = 0; c < 64; ++c) qrow[c] = b2f(qch[t * 72 + c]);
#pragma unroll 4
      for (int s = 0; s < 32; ++s) {
        float a = 0.f;
#pragma unroll
        for (int c = 0; c < 64; ++c) a += qrow[c] * b2f(mh[s * 64 + c]);
        acc32[s] += a;
      }
    }
    float zs[32];
#pragma unroll
    for (int i = 0; i < 32; ++i) zs[i] = acc32[i];
#pragma unroll
    for (int kk = 2; kk <= 32; kk <<= 1) {
#pragma unroll
      for (int j = kk >> 1; j > 0; j >>= 1) {
#pragma unroll
        for (int i = 0; i < 32; ++i) {
          int ij = i ^ j;
          if (ij > i) {
            bool up = ((i & kk) == 0);
            float a = zs[i], bq_ = zs[ij];
            float hi = fmaxf(a, bq_), lo = fminf(a, bq_);
            zs[i]  = up ? hi : lo;
            zs[ij] = up ? lo : hi;
          }
        }
      }
    }
    float cum = 0.f, cumsel = 0.f;
    int ksup = 1;
#pragma unroll
    for (int i = 0; i < 32; ++i) {
      cum += zs[i];
      if (1.f + (float)(i + 1) * zs[i] > cum) { ksup = i + 1; cumsel = cum; }
    }
    float tau = (cumsel - 1.f) / (float)ksup;
#pragma unroll
    for (int s = 0; s < 32; ++s) sc[t * 32 + s] = fmaxf(acc32[s] - tau, 0.f);
    __syncthreads();
    for (int jj = 0; jj < 4; ++jj) {
      int j = t + jj * 256;
      const u16* nrow = N2t + ((size_t)h * 1024 + j) * 512;
      float acc16[16];
#pragma unroll
      for (int a = 0; a < 16; ++a) acc16[a] = 0.f;
      for (int k0 = 0; k0 < 512; k0 += 8) {
        union { uint4 v; u16 w[8]; } nv __attribute__((aligned(16)));
        nv.v = *(const uint4*)(nrow + k0);
#pragma unroll
        for (int kk = 0; kk < 8; ++kk) {
          float nf = b2f(nv.w[kk]);
#pragma unroll
          for (int a = 0; a < 16; ++a) acc16[a] += sc[a * 512 + k0 + kk] * nf;
        }
      }
      float bj = bo_f[j];
#pragma unroll
      for (int a = 0; a < 16; ++a) {
        int orow = b * 4096 + h * 256 + atile * 16 + a;
        size_t oi = (size_t)orow * 1024 + j;
        float v = acc16[a] + bj;
        if (f32) ((float*)out)[oi] = v;
        else     ((u16*)out)[oi] = f2b(v);
      }
    }
    __syncthreads();
  }
}

__global__ void zero_out(void* __restrict__ out, int n, const int* __restrict__ flag) {
  const int f32 = *flag;
  int i = blockIdx.x * 256 + threadIdx.x;
  if (i < n) { if (f32) ((float*)out)[i] = 0.f; else ((u16*)out)[i] = 0; }
}

extern "C" void kernel_launch(void* const* d_in, const int* in_sizes, int n_in,
                              void* d_out, int out_size, void* d_ws, size_t ws_size,
                              hipStream_t stream) {
  const void* query = d_in[0];
  const void* kp    = d_in[1];
  const void* Wq    = d_in[2];
  const void* bq    = d_in[3];
  const void* Wk    = d_in[4];
  const void* bk    = d_in[5];
  const void* Wv    = d_in[6];
  const void* bv    = d_in[7];
  const void* Wo    = d_in[8];
  const void* bo    = d_in[9];

  char* ws = (char*)d_ws;
  int*   flag   = (int*)(ws);                      // 4 B @ 0
  float* Kf     = (float*)(ws + (64 << 10));       // 128 KB
  float* Vf     = (float*)(ws + (192 << 10));      // 128 KB
  float* bias_s = (float*)(ws + (320 << 10));      // 2 KB
  float* bo_f   = (float*)(ws + (324 << 10));      // 4 KB
  u16*   Mt     = (u16*)(ws + (1 << 20));          // 1 MB
  u16*   N2t    = (u16*)(ws + (2 << 20));          // 16 MB
  u16*   Z2     = (u16*)(ws + (18 << 20));         // 32 MB (fast path only)
  // K/V k-split partials: 4 MB, OVERLAPS Z2 (safe: K/V prep completes before
  // gemm_scores writes Z2; same stream).
  float* Pp     = (float*)(ws + (18 << 20));

  const size_t WS_FAST = (size_t)(18 << 20) + 33554432;   // 50 MB
  const size_t WS_FALL = (size_t)(18 << 20);              // 18 MB

  sniff_k<<<1, 256, 0, stream>>>(query, flag);

  if (ws_size >= WS_FAST) {
    // K = kp @ Wk + bk   (k-split: 128 blocks, latency-tolerant)
    gemm32_part<<<dim3(4, 32), 256, 0, stream>>>(kp, Wk, Pp, flag, 0);
    gemm32_reduce<<<128, 256, 0, stream>>>(Pp, bk, Kf, flag);
    // V = Kf @ Wv + bv
    gemm32_part<<<dim3(4, 32), 256, 0, stream>>>(Kf, Wv, Pp, flag, 1);
    gemm32_reduce<<<128, 256, 0, stream>>>(Pp, bv, Vf, flag);
    kernel_M<<<512, 256, 0, stream>>>(Kf, Wq, bq, Mt, bias_s, flag);
    kernel_N2<<<1024, 256, 0, stream>>>(Vf, Wo, N2t, flag);
    kernel_bo<<<4, 256, 0, stream>>>(bo, bo_f, flag);
    gemm_scores<<<dim3(512 / 128, 32768 / 128), 256, 0, stream>>>(query, Mt, bias_s, Z2, flag);
    sparsemax_k<<<2048, 256, 0, stream>>>(Z2);
    gemm_out<<<dim3(1024 / 128, 2048 / 128, 16), 256, 0, stream>>>(Z2, N2t, bo_f, d_out, flag);
  } else if (ws_size >= WS_FALL) {
    kernel_K<<<128, 256, 0, stream>>>(kp, Wk, bk, Kf, flag);
    kernel_V<<<128, 256, 0, stream>>>(Kf, Wv, bv, Vf, flag);
    kernel_M<<<512, 256, 0, stream>>>(Kf, Wq, bq, Mt, bias_s, flag);
    kernel_N2<<<1024, 256, 0, stream>>>(Vf, Wo, N2t, flag);
    kernel_bo<<<4, 256, 0, stream>>>(bo, bo_f, flag);
    fused_fallback<<<128, 256, 0, stream>>>(query, Mt, bias_s, N2t, bo_f, d_out, flag);
  } else {
    zero_out<<<(out_size + 255) / 256, 256, 0, stream>>>(d_out, out_size, flag);
  }
}

// Round 2
// 518.052 us; speedup vs baseline: 1.5164x; 1.5164x over previous
//
#include <hip/hip_runtime.h>

typedef unsigned short u16;
typedef __attribute__((ext_vector_type(8))) short short8;
typedef __attribute__((ext_vector_type(4))) float v4f;

__device__ __forceinline__ float b2f(u16 u) {
  union { unsigned int i; float f; } v; v.i = ((unsigned int)u) << 16; return v.f;
}
__device__ __forceinline__ u16 f2b(float f) {
  unsigned int x = __float_as_uint(f);
  x += 0x7fffu + ((x >> 16) & 1u);   // RNE
  return (u16)(x >> 16);
}
// dtype-flexible input load: f32 ? fp32 array : bf16(u16) array
__device__ __forceinline__ float ldin(const void* p, size_t i, int f32) {
  return f32 ? ((const float*)p)[i] : b2f(((const u16*)p)[i]);
}

// ---------------- dtype sniff: bf16 vs fp32, from query's raw bits ----------------
__global__ void sniff_k(const void* __restrict__ q, int* __restrict__ flag) {
  __shared__ int cnt;
  if (threadIdx.x == 0) cnt = 0;
  __syncthreads();
  const u16* p = (const u16*)q;
  int w = 0;
  for (int i = threadIdx.x; i < 1024; i += 256) {
    u16 u = p[i];
    int e = (u >> 7) & 0xFF;
    if (u != 0 && u != 0x8000 && (e >= 0xC0 || e < 0x40)) w++;
  }
  atomicAdd(&cnt, w);
  __syncthreads();
  if (threadIdx.x == 0) *flag = (cnt >= 32) ? 1 : 0;   // wild bits => fp32
}

// ---------------- zero-init for atomic split-K outputs ----------------
__global__ void kv_zero(float* __restrict__ Kf, float* __restrict__ Vf) {
  int i = blockIdx.x * 256 + threadIdx.x;   // 32768
  Kf[i] = 0.f;
  Vf[i] = 0.f;
}

// ---------------- skinny 32x1024 GEMM, split-K=8 via fp32 atomics ----------------
// C[t] += bias (kb==0) + sum_{d in chunk} A[s][d] * W[d][j];  t = s*1024+j
// grid dim3(128, 8) x 256 thr. 1024 blocks = 16 waves/CU -> latency-tolerant.
// a_f32_always=1 => A is fp32 regardless of input dtype flag.
__global__ void gemm_skinny_atomic(const void* __restrict__ A, const void* __restrict__ W,
                                   const void* __restrict__ bias, float* __restrict__ C,
                                   const int* __restrict__ flag, int a_f32_always) {
  const int f32 = *flag;
  const int af = a_f32_always ? 1 : f32;
  const int t = blockIdx.x * 256 + threadIdx.x;   // 0..32767
  const int kb = blockIdx.y;                      // 0..7
  const int s = t >> 10, j = t & 1023;
  const int d0 = kb * 128;
  float acc = 0.f;
#pragma unroll 16
  for (int d = d0; d < d0 + 128; ++d)
    acc += ldin(A, (size_t)s * 1024 + d, af) * ldin(W, (size_t)d * 1024 + j, f32);
  if (kb == 0) acc += ldin(bias, j, f32);
  atomicAdd(&C[t], acc);
}

// ---------------- prep (fallback path only): K = key_param @ Wk + bk --------------
__global__ void kernel_K(const void* __restrict__ kp, const void* __restrict__ Wk,
                         const void* __restrict__ bk, float* __restrict__ Kf,
                         const int* __restrict__ flag) {
  const int f32 = *flag;
  int t = blockIdx.x * 256 + threadIdx.x;   // 32768 = 32 s x 1024 j
  int s = t >> 10, j = t & 1023;
  float acc = 0.f;
#pragma unroll 8
  for (int d = 0; d < 1024; ++d)
    acc += ldin(kp, (size_t)s * 1024 + d, f32) * ldin(Wk, (size_t)d * 1024 + j, f32);
  Kf[t] = acc + ldin(bk, j, f32);
}

// ---------------- prep (fallback path only): V = K @ Wv + bv ----------------
__global__ void kernel_V(const float* __restrict__ Kf, const void* __restrict__ Wv,
                         const void* __restrict__ bv, float* __restrict__ Vf,
                         const int* __restrict__ flag) {
  const int f32 = *flag;
  int t = blockIdx.x * 256 + threadIdx.x;
  int s = t >> 10, j = t & 1023;
  const float* kr = Kf + (size_t)s * 1024;
  float acc = 0.f;
#pragma unroll 8
  for (int d = 0; d < 1024; ++d) acc += kr[d] * ldin(Wv, (size_t)d * 1024 + j, f32);
  Vf[t] = acc + ldin(bv, j, f32);
}

// ---------------- prep: Mt[hs][d] = (1/8) sum_e Wq[d, h*64+e] * K[s, h*64+e] ------
__global__ void kernel_M(const float* __restrict__ Kf, const void* __restrict__ Wq,
                         const void* __restrict__ bq, u16* __restrict__ Mt,
                         float* __restrict__ bias_s, const int* __restrict__ flag) {
  const int f32 = *flag;
  int b = blockIdx.x;               // b = h*32+s = hs
  int h = b >> 5, s = b & 31, tid = threadIdx.x;
  __shared__ float ksl[64];
  if (tid < 64) ksl[tid] = Kf[(size_t)s * 1024 + h * 64 + tid] * 0.125f;  // fold 1/sqrt(64)
  __syncthreads();
#pragma unroll
  for (int r = 0; r < 4; ++r) {
    int d = tid + r * 256;
    float acc = 0.f;
#pragma unroll
    for (int e = 0; e < 64; ++e)
      acc += ldin(Wq, (size_t)d * 1024 + h * 64 + e, f32) * ksl[e];
    Mt[(size_t)b * 1024 + d] = f2b(acc);
  }
  if (tid == 0) {
    float acc = 0.f;
    for (int e = 0; e < 64; ++e) acc += ldin(bq, h * 64 + e, f32) * ksl[e];
    bias_s[b] = acc;
  }
}

// ---------------- prep: N2t[h][j][r*32+s] = sum_d V[s, h*64+d] * Wo[r*64+d, j] ----
__global__ void kernel_N2(const float* __restrict__ Vf, const void* __restrict__ Wo,
                          u16* __restrict__ N2t, const int* __restrict__ flag) {
  const int f32 = *flag;
  int blk = blockIdx.x;             // 1024 blocks: h(16) x r(16) x jb(4)
  int h = blk >> 6, r = (blk >> 2) & 15, jb = blk & 3;
  int tid = threadIdx.x;
  int j = jb * 256 + tid;
  __shared__ float vsl[2048];       // V[s=0..31][d=0..63] for this h
  for (int i = tid; i < 2048; i += 256) {
    int s = i >> 6, d = i & 63;
    vsl[i] = Vf[(size_t)s * 1024 + h * 64 + d];
  }
  __syncthreads();
  float acc[32];
#pragma unroll
  for (int s = 0; s < 32; ++s) acc[s] = 0.f;
  for (int d = 0; d < 64; ++d) {
    float w = ldin(Wo, (size_t)(r * 64 + d) * 1024 + j, f32);
#pragma unroll
    for (int s = 0; s < 32; ++s) acc[s] += vsl[s * 64 + d] * w;
  }
  union { u16 o[32]; uint4 v[4]; } ou __attribute__((aligned(16)));
#pragma unroll
  for (int s = 0; s < 32; ++s) ou.o[s] = f2b(acc[s]);
  uint4* dst = (uint4*)(N2t + ((size_t)(h * 1024 + j)) * 512 + r * 32);
#pragma unroll
  for (int i = 0; i < 4; ++i) dst[i] = ou.v[i];
}

// ---------------- prep: bo -> fp32 ----------------
__global__ void kernel_bo(const void* __restrict__ bo, float* __restrict__ bo_f,
                          const int* __restrict__ flag) {
  const int f32 = *flag;
  int i = blockIdx.x * 256 + threadIdx.x;
  if (i < 1024) bo_f[i] = ldin(bo, i, f32);
}

// ---------------- GEMM1: Z2 = query @ Mt^T + bias_s, written permuted -------------
// C[rw][col] (rw in [0,32768), col=hs in [0,512)) -> Z2[h][rw>>4][(rw&15)*32 + s]
__global__ void gemm_scores(const void* __restrict__ A, const u16* __restrict__ B,
                            const float* __restrict__ bias, u16* __restrict__ Z2,
                            const int* __restrict__ flag) {
  const int f32 = *flag;
  const int K = 1024;
  __shared__ u16 As[128 * 32] __attribute__((aligned(16)));
  __shared__ u16 Bs[128 * 32] __attribute__((aligned(16)));
  const int tid = threadIdx.x;
  const int wave = tid >> 6;
  const int lane = tid & 63;
  const int quad = lane >> 4;
  const int l16 = lane & 15;
  const int m0 = blockIdx.y * 128;
  const int n0 = blockIdx.x * 128;
  const int wm = (wave >> 1) * 64;
  const int wn = (wave & 1) * 64;

  v4f acc[4][4] = {};

  const int idx0 = tid, idx1 = 256 + tid;
  const int r0 = idx0 >> 2, c0 = (idx0 & 3) * 8;
  const int r1 = idx1 >> 2, c1 = (idx1 & 3) * 8;
  const u16* Bb = B + (size_t)n0 * K;

  for (int k0 = 0; k0 < K; k0 += 32) {
    size_t offA0 = (size_t)(m0 + r0) * K + k0 + c0;
    size_t offA1 = (size_t)(m0 + r1) * K + k0 + c1;
    if (!f32) {
      *(uint4*)&As[idx0 * 8] = *(const uint4*)((const u16*)A + offA0);
      *(uint4*)&As[idx1 * 8] = *(const uint4*)((const u16*)A + offA1);
    } else {
      const float* fA = (const float*)A;
      // 32B-aligned offsets (k0%32==0, c0%8==0) -> vector loads
      v4f a0 = *(const v4f*)(fA + offA0);
      v4f a1 = *(const v4f*)(fA + offA0 + 4);
      v4f a2 = *(const v4f*)(fA + offA1);
      v4f a3 = *(const v4f*)(fA + offA1 + 4);
      union { uint4 v; u16 w[8]; } t0 __attribute__((aligned(16)));
      union { uint4 v; u16 w[8]; } t1 __attribute__((aligned(16)));
#pragma unroll
      for (int e = 0; e < 4; ++e) { t0.w[e] = f2b(a0[e]); t0.w[e + 4] = f2b(a1[e]); }
#pragma unroll
      for (int e = 0; e < 4; ++e) { t1.w[e] = f2b(a2[e]); t1.w[e + 4] = f2b(a3[e]); }
      *(uint4*)&As[idx0 * 8] = t0.v;
      *(uint4*)&As[idx1 * 8] = t1.v;
    }
    *(uint4*)&Bs[idx0 * 8] = *(const uint4*)(Bb + (size_t)r0 * K + k0 + c0);
    *(uint4*)&Bs[idx1 * 8] = *(const uint4*)(Bb + (size_t)r1 * K + k0 + c1);
    __syncthreads();
    short8 af[4], bf[4];
#pragma unroll
    for (int i = 0; i < 4; ++i)
      af[i] = *(const short8*)&As[(wm + i * 16 + l16) * 32 + quad * 8];
#pragma unroll
    for (int i = 0; i < 4; ++i)
      bf[i] = *(const short8*)&Bs[(wn + i * 16 + l16) * 32 + quad * 8];
#pragma unroll
    for (int mi = 0; mi < 4; ++mi)
#pragma unroll
      for (int ni = 0; ni < 4; ++ni)
        acc[mi][ni] = __builtin_amdgcn_mfma_f32_16x16x32_bf16(af[mi], bf[ni], acc[mi][ni], 0, 0, 0);
    __syncthreads();
  }

#pragma unroll
  for (int ni = 0; ni < 4; ++ni) {
    const int col = n0 + wn + ni * 16 + l16;
    const float bcol = bias[col];
    const int h = col >> 5, s = col & 31;
#pragma unroll
    for (int mi = 0; mi < 4; ++mi) {
      const int rbase = m0 + wm + mi * 16 + quad * 4;
#pragma unroll
      for (int rr = 0; rr < 4; ++rr) {
        const int rw = rbase + rr;
        const size_t addr = (size_t)h * 1048576 + (size_t)(rw >> 4) * 512 + (rw & 15) * 32 + s;
        Z2[addr] = f2b(acc[mi][ni][rr] + bcol);
      }
    }
  }
}

// ---------------- sparsemax over groups of 32, in place on Z2 (bf16) --------------
__global__ void sparsemax_k(u16* __restrict__ Z) {
  int t = blockIdx.x * 256 + threadIdx.x;   // 524288 groups of 32
  u16* zp = Z + (size_t)t * 32;
  union { uint4 v[4]; u16 w[32]; } raw __attribute__((aligned(16)));
  const uint4* rp4 = (const uint4*)zp;
#pragma unroll
  for (int i = 0; i < 4; ++i) raw.v[i] = rp4[i];
  float z[32], zs[32];
#pragma unroll
  for (int i = 0; i < 32; ++i) { z[i] = b2f(raw.w[i]); zs[i] = z[i]; }
#pragma unroll
  for (int kk = 2; kk <= 32; kk <<= 1) {
#pragma unroll
    for (int j = kk >> 1; j > 0; j >>= 1) {
#pragma unroll
      for (int i = 0; i < 32; ++i) {
        int ij = i ^ j;
        if (ij > i) {
          bool up = ((i & kk) == 0);
          float a = zs[i], b = zs[ij];
          float hi = fmaxf(a, b), lo = fminf(a, b);
          zs[i]  = up ? hi : lo;
          zs[ij] = up ? lo : hi;
        }
      }
    }
  }
  float cum = 0.f, cumsel = 0.f;
  int ksup = 1;
#pragma unroll
  for (int i = 0; i < 32; ++i) {
    cum += zs[i];
    if (1.f + (float)(i + 1) * zs[i] > cum) { ksup = i + 1; cumsel = cum; }
  }
  float tau = (cumsel - 1.f) / (float)ksup;
  union { u16 o[32]; uint4 v[4]; } ou __attribute__((aligned(16)));
#pragma unroll
  for (int i = 0; i < 32; ++i) ou.o[i] = f2b(fmaxf(z[i] - tau, 0.f));
  uint4* op = (uint4*)zp;
#pragma unroll
  for (int i = 0; i < 4; ++i) op[i] = ou.v[i];
}

// ---------------- GEMM2 (batched over h): out_h = A_sp_h @ N2t_h^T + bo -----------
__global__ void gemm_out(const u16* __restrict__ Z2, const u16* __restrict__ N2t,
                         const float* __restrict__ bias, void* __restrict__ out,
                         const int* __restrict__ flag) {
  const int f32 = *flag;
  const int K = 512;
  const int h = blockIdx.z;
  __shared__ u16 As[128 * 32] __attribute__((aligned(16)));
  __shared__ u16 Bs[128 * 32] __attribute__((aligned(16)));
  const int tid = threadIdx.x;
  const int wave = tid >> 6;
  const int lane = tid & 63;
  const int quad = lane >> 4;
  const int l16 = lane & 15;
  const int m0 = blockIdx.y * 128;
  const int n0 = blockIdx.x * 128;
  const int wm = (wave >> 1) * 64;
  const int wn = (wave & 1) * 64;

  v4f acc[4][4] = {};

  const u16* Ab = Z2 + (size_t)h * 2048 * 512 + (size_t)m0 * K;
  const u16* Bb = N2t + (size_t)h * 1024 * 512 + (size_t)n0 * K;
  const int idx0 = tid, idx1 = 256 + tid;
  const int r0 = idx0 >> 2, c0 = (idx0 & 3) * 8;
  const int r1 = idx1 >> 2, c1 = (idx1 & 3) * 8;

  for (int k0 = 0; k0 < K; k0 += 32) {
    *(uint4*)&As[idx0 * 8] = *(const uint4*)(Ab + (size_t)r0 * K + k0 + c0);
    *(uint4*)&As[idx1 * 8] = *(const uint4*)(Ab + (size_t)r1 * K + k0 + c1);
    *(uint4*)&Bs[idx0 * 8] = *(const uint4*)(Bb + (size_t)r0 * K + k0 + c0);
    *(uint4*)&Bs[idx1 * 8] = *(const uint4*)(Bb + (size_t)r1 * K + k0 + c1);
    __syncthreads();
    short8 af[4], bf[4];
#pragma unroll
    for (int i = 0; i < 4; ++i)
      af[i] = *(const short8*)&As[(wm + i * 16 + l16) * 32 + quad * 8];
#pragma unroll
    for (int i = 0; i < 4; ++i)
      bf[i] = *(const short8*)&Bs[(wn + i * 16 + l16) * 32 + quad * 8];
#pragma unroll
    for (int mi = 0; mi < 4; ++mi)
#pragma unroll
      for (int ni = 0; ni < 4; ++ni)
        acc[mi][ni] = __builtin_amdgcn_mfma_f32_16x16x32_bf16(af[mi], bf[ni], acc[mi][ni], 0, 0, 0);
    __syncthreads();
  }

  float bv4[4];
#pragma unroll
  for (int ni = 0; ni < 4; ++ni) bv4[ni] = bias[n0 + wn + ni * 16 + l16];
#pragma unroll
  for (int mi = 0; mi < 4; ++mi) {
    const int rl = m0 + wm + mi * 16 + quad * 4;
#pragma unroll
    for (int rr = 0; rr < 4; ++rr) {
      const int rlr = rl + rr;
      const int orow = (rlr >> 8) * 4096 + h * 256 + (rlr & 255);
#pragma unroll
      for (int ni = 0; ni < 4; ++ni) {
        const int col = n0 + wn + ni * 16 + l16;
        const float v = acc[mi][ni][rr] + bv4[ni];
        const size_t oi = (size_t)orow * 1024 + col;
        if (f32) ((float*)out)[oi] = v;
        else     ((u16*)out)[oi] = f2b(v);
      }
    }
  }
}

// ---------------- ws-light fused fallback ----------------
__global__ void __launch_bounds__(256) fused_fallback(
    const void* __restrict__ query, const u16* __restrict__ Mt,
    const float* __restrict__ bias_s, const u16* __restrict__ N2t,
    const float* __restrict__ bo_f, void* __restrict__ out,
    const int* __restrict__ flag) {
  const int f32 = *flag;
  __shared__ float sc[256 * 32];
  __shared__ u16 qch[256 * 72];
  __shared__ u16 mh[32 * 64];
  const int t = threadIdx.x;
  const int bb = blockIdx.x;              // 128 blocks: b(8) x atile(16)
  const int b = bb >> 4, atile = bb & 15;
  const int l0 = atile * 256;
  const size_t qbase = ((size_t)b * 4096 + l0) * 1024;

  for (int h = 0; h < 16; ++h) {
    float acc32[32];
#pragma unroll
    for (int s = 0; s < 32; ++s) acc32[s] = bias_s[h * 32 + s];
    for (int d0 = 0; d0 < 1024; d0 += 64) {
      __syncthreads();
#pragma unroll
      for (int i = 0; i < 8; ++i) {
        int f4 = t + i * 256;
        int row = f4 >> 3, c8 = f4 & 7;
        size_t off = qbase + (size_t)row * 1024 + d0 + c8 * 8;
        if (!f32) {
          *(uint4*)&qch[row * 72 + c8 * 8] = *(const uint4*)((const u16*)query + off);
        } else {
          union { uint4 v; u16 w[8]; } tq __attribute__((aligned(16)));
#pragma unroll
          for (int e = 0; e < 8; ++e) tq.w[e] = f2b(((const float*)query)[off + e]);
          *(uint4*)&qch[row * 72 + c8 * 8] = tq.v;
        }
      }
      { int row = t >> 3, c8 = t & 7;
        *(uint4*)&mh[row * 64 + c8 * 8] =
            *(const uint4*)(Mt + (size_t)(h * 32 + row) * 1024 + d0 + c8 * 8); }
      __syncthreads();
      float qrow[64];
#pragma unroll
      for (int c = 0; c < 64; ++c) qrow[c] = b2f(qch[t * 72 + c]);
#pragma unroll 4
      for (int s = 0; s < 32; ++s) {
        float a = 0.f;
#pragma unroll
        for (int c = 0; c < 64; ++c) a += qrow[c] * b2f(mh[s * 64 + c]);
        acc32[s] += a;
      }
    }
    float zs[32];
#pragma unroll
    for (int i = 0; i < 32; ++i) zs[i] = acc32[i];
#pragma unroll
    for (int kk = 2; kk <= 32; kk <<= 1) {
#pragma unroll
      for (int j = kk >> 1; j > 0; j >>= 1) {
#pragma unroll
        for (int i = 0; i < 32; ++i) {
          int ij = i ^ j;
          if (ij > i) {
            bool up = ((i & kk) == 0);
            float a = zs[i], bq_ = zs[ij];
            float hi = fmaxf(a, bq_), lo = fminf(a, bq_);
            zs[i]  = up ? hi : lo;
            zs[ij] = up ? lo : hi;
          }
        }
      }
    }
    float cum = 0.f, cumsel = 0.f;
    int ksup = 1;
#pragma unroll
    for (int i = 0; i < 32; ++i) {
      cum += zs[i];
      if (1.f + (float)(i + 1) * zs[i] > cum) { ksup = i + 1; cumsel = cum; }
    }
    float tau = (cumsel - 1.f) / (float)ksup;
#pragma unroll
    for (int s = 0; s < 32; ++s) sc[t * 32 + s] = fmaxf(acc32[s] - tau, 0.f);
    __syncthreads();
    for (int jj = 0; jj < 4; ++jj) {
      int j = t + jj * 256;
      const u16* nrow = N2t + ((size_t)h * 1024 + j) * 512;
      float acc16[16];
#pragma unroll
      for (int a = 0; a < 16; ++a) acc16[a] = 0.f;
      for (int k0 = 0; k0 < 512; k0 += 8) {
        union { uint4 v; u16 w[8]; } nv __attribute__((aligned(16)));
        nv.v = *(const uint4*)(nrow + k0);
#pragma unroll
        for (int kk = 0; kk < 8; ++kk) {
          float nf = b2f(nv.w[kk]);
#pragma unroll
          for (int a = 0; a < 16; ++a) acc16[a] += sc[a * 512 + k0 + kk] * nf;
        }
      }
      float bj = bo_f[j];
#pragma unroll
      for (int a = 0; a < 16; ++a) {
        int orow = b * 4096 + h * 256 + atile * 16 + a;
        size_t oi = (size_t)orow * 1024 + j;
        float v = acc16[a] + bj;
        if (f32) ((float*)out)[oi] = v;
        else     ((u16*)out)[oi] = f2b(v);
      }
    }
    __syncthreads();
  }
}

__global__ void zero_out(void* __restrict__ out, int n, const int* __restrict__ flag) {
  const int f32 = *flag;
  int i = blockIdx.x * 256 + threadIdx.x;
  if (i < n) { if (f32) ((float*)out)[i] = 0.f; else ((u16*)out)[i] = 0; }
}

extern "C" void kernel_launch(void* const* d_in, const int* in_sizes, int n_in,
                              void* d_out, int out_size, void* d_ws, size_t ws_size,
                              hipStream_t stream) {
  const void* query = d_in[0];
  const void* kp    = d_in[1];
  const void* Wq    = d_in[2];
  const void* bq    = d_in[3];
  const void* Wk    = d_in[4];
  const void* bk    = d_in[5];
  const void* Wv    = d_in[6];
  const void* bv    = d_in[7];
  const void* Wo    = d_in[8];
  const void* bo    = d_in[9];

  char* ws = (char*)d_ws;
  int*   flag   = (int*)(ws);                      // 4 B @ 0
  float* Kf     = (float*)(ws + (64 << 10));       // 128 KB
  float* Vf     = (float*)(ws + (192 << 10));      // 128 KB
  float* bias_s = (float*)(ws + (320 << 10));      // 2 KB
  float* bo_f   = (float*)(ws + (324 << 10));      // 4 KB
  u16*   Mt     = (u16*)(ws + (1 << 20));          // 1 MB
  u16*   N2t    = (u16*)(ws + (2 << 20));          // 16 MB
  u16*   Z2     = (u16*)(ws + (18 << 20));         // 32 MB (fast path only)

  const size_t WS_FAST = (size_t)(18 << 20) + 33554432;   // 50 MB
  const size_t WS_FALL = (size_t)(18 << 20);              // 18 MB

  sniff_k<<<1, 256, 0, stream>>>(query, flag);

  if (ws_size >= WS_FAST) {
    // K = kp @ Wk + bk ; V = Kf @ Wv + bv   (split-K=8, fp32 atomic accumulate)
    kv_zero<<<128, 256, 0, stream>>>(Kf, Vf);
    gemm_skinny_atomic<<<dim3(128, 8), 256, 0, stream>>>(kp, Wk, bk, Kf, flag, 0);
    gemm_skinny_atomic<<<dim3(128, 8), 256, 0, stream>>>(Kf, Wv, bv, Vf, flag, 1);
    kernel_M<<<512, 256, 0, stream>>>(Kf, Wq, bq, Mt, bias_s, flag);
    kernel_N2<<<1024, 256, 0, stream>>>(Vf, Wo, N2t, flag);
    kernel_bo<<<4, 256, 0, stream>>>(bo, bo_f, flag);
    gemm_scores<<<dim3(512 / 128, 32768 / 128), 256, 0, stream>>>(query, Mt, bias_s, Z2, flag);
    sparsemax_k<<<2048, 256, 0, stream>>>(Z2);
    gemm_out<<<dim3(1024 / 128, 2048 / 128, 16), 256, 0, stream>>>(Z2, N2t, bo_f, d_out, flag);
  } else if (ws_size >= WS_FALL) {
    kernel_K<<<128, 256, 0, stream>>>(kp, Wk, bk, Kf, flag);
    kernel_V<<<128, 256, 0, stream>>>(Kf, Wv, bv, Vf, flag);
    kernel_M<<<512, 256, 0, stream>>>(Kf, Wq, bq, Mt, bias_s, flag);
    kernel_N2<<<1024, 256, 0, stream>>>(Vf, Wo, N2t, flag);
    kernel_bo<<<4, 256, 0, stream>>>(bo, bo_f, flag);
    fused_fallback<<<128, 256, 0, stream>>>(query, Mt, bias_s, N2t, bo_f, d_out, flag);
  } else {
    zero_out<<<(out_size + 255) / 256, 256, 0, stream>>>(d_out, out_size, flag);
  }
}

// Round 3
// 464.875 us; speedup vs baseline: 1.6898x; 1.1144x over previous
//
#include <hip/hip_runtime.h>

typedef unsigned short u16;
typedef __attribute__((ext_vector_type(8))) short short8;
typedef __attribute__((ext_vector_type(4))) float v4f;

__device__ __forceinline__ float b2f(u16 u) {
  union { unsigned int i; float f; } v; v.i = ((unsigned int)u) << 16; return v.f;
}
__device__ __forceinline__ u16 f2b(float f) {
  unsigned int x = __float_as_uint(f);
  x += 0x7fffu + ((x >> 16) & 1u);   // RNE
  return (u16)(x >> 16);
}
// dtype-flexible input load: f32 ? fp32 array : bf16(u16) array
__device__ __forceinline__ float ldin(const void* p, size_t i, int f32) {
  return f32 ? ((const float*)p)[i] : b2f(((const u16*)p)[i]);
}

// LDS row stride for 128x32-u16 GEMM tiles, padded 32->40 u16 (80 B) so that
// ds_read_b128 column reads hit banks at stride 20 -> 2-deep/16 lanes (free).
#define LDSW 40

// ---------------- dtype sniff: bf16 vs fp32, from query's raw bits ----------------
__global__ void sniff_k(const void* __restrict__ q, int* __restrict__ flag) {
  __shared__ int cnt;
  if (threadIdx.x == 0) cnt = 0;
  __syncthreads();
  const u16* p = (const u16*)q;
  int w = 0;
  for (int i = threadIdx.x; i < 1024; i += 256) {
    u16 u = p[i];
    int e = (u >> 7) & 0xFF;
    if (u != 0 && u != 0x8000 && (e >= 0xC0 || e < 0x40)) w++;
  }
  atomicAdd(&cnt, w);
  __syncthreads();
  if (threadIdx.x == 0) *flag = (cnt >= 32) ? 1 : 0;   // wild bits => fp32
}

// ---------------- zero-init for atomic split-K outputs ----------------
__global__ void kv_zero(float* __restrict__ Kf, float* __restrict__ Vf) {
  int i = blockIdx.x * 256 + threadIdx.x;   // 32768
  Kf[i] = 0.f;
  Vf[i] = 0.f;
}

// ---------------- skinny 32x1024 GEMM, split-K=8 via fp32 atomics ----------------
__global__ void gemm_skinny_atomic(const void* __restrict__ A, const void* __restrict__ W,
                                   const void* __restrict__ bias, float* __restrict__ C,
                                   const int* __restrict__ flag, int a_f32_always) {
  const int f32 = *flag;
  const int af = a_f32_always ? 1 : f32;
  const int t = blockIdx.x * 256 + threadIdx.x;   // 0..32767
  const int kb = blockIdx.y;                      // 0..7
  const int s = t >> 10, j = t & 1023;
  const int d0 = kb * 128;
  float acc = 0.f;
#pragma unroll 16
  for (int d = d0; d < d0 + 128; ++d)
    acc += ldin(A, (size_t)s * 1024 + d, af) * ldin(W, (size_t)d * 1024 + j, f32);
  if (kb == 0) acc += ldin(bias, j, f32);
  atomicAdd(&C[t], acc);
}

// ---------------- prep (fallback path only): K = key_param @ Wk + bk --------------
__global__ void kernel_K(const void* __restrict__ kp, const void* __restrict__ Wk,
                         const void* __restrict__ bk, float* __restrict__ Kf,
                         const int* __restrict__ flag) {
  const int f32 = *flag;
  int t = blockIdx.x * 256 + threadIdx.x;   // 32768 = 32 s x 1024 j
  int s = t >> 10, j = t & 1023;
  float acc = 0.f;
#pragma unroll 8
  for (int d = 0; d < 1024; ++d)
    acc += ldin(kp, (size_t)s * 1024 + d, f32) * ldin(Wk, (size_t)d * 1024 + j, f32);
  Kf[t] = acc + ldin(bk, j, f32);
}

// ---------------- prep (fallback path only): V = K @ Wv + bv ----------------
__global__ void kernel_V(const float* __restrict__ Kf, const void* __restrict__ Wv,
                         const void* __restrict__ bv, float* __restrict__ Vf,
                         const int* __restrict__ flag) {
  const int f32 = *flag;
  int t = blockIdx.x * 256 + threadIdx.x;
  int s = t >> 10, j = t & 1023;
  const float* kr = Kf + (size_t)s * 1024;
  float acc = 0.f;
#pragma unroll 8
  for (int d = 0; d < 1024; ++d) acc += kr[d] * ldin(Wv, (size_t)d * 1024 + j, f32);
  Vf[t] = acc + ldin(bv, j, f32);
}

// ---------------- prep: Mt[hs][d] = (1/8) sum_e Wq[d, h*64+e] * K[s, h*64+e] ------
// Vectorized rewrite: 256 blocks = h(16) x dgrp(16); thread t: d = dgrp*64+(t&63),
// s-range = (t>>6)*8 .. +7. Wq loaded as float4/uint4 (64 contiguous elems/lane),
// K-slice staged in LDS as ks2[e][s] (*0.125), read as broadcast v4f.
__global__ void __launch_bounds__(256) kernel_M2(
    const float* __restrict__ Kf, const void* __restrict__ Wq,
    const void* __restrict__ bq, u16* __restrict__ Mt,
    float* __restrict__ bias_s, const int* __restrict__ flag) {
  const int f32 = *flag;
  const int blk = blockIdx.x;
  const int h = blk >> 4, dg = blk & 15;
  const int t = threadIdx.x;
  const int d = dg * 64 + (t & 63);
  const int sb = (t >> 6) * 8;
  __shared__ float ks2[64][32];     // [e][s], scaled by 0.125
  for (int i = t; i < 2048; i += 256) {
    int s = i & 31, e = i >> 5;     // s in low bits: LDS write banks = s -> conflict-free
    ks2[e][s] = Kf[(size_t)s * 1024 + h * 64 + e] * 0.125f;
  }
  __syncthreads();
  v4f a0 = {0.f, 0.f, 0.f, 0.f}, a1 = {0.f, 0.f, 0.f, 0.f};
  const size_t base = (size_t)d * 1024 + h * 64;
  for (int e0 = 0; e0 < 64; e0 += 8) {
    float wq[8];
    if (f32) {
      const float* W = (const float*)Wq;
      v4f v0 = *(const v4f*)(W + base + e0);
      v4f v1 = *(const v4f*)(W + base + e0 + 4);
#pragma unroll
      for (int q = 0; q < 4; ++q) { wq[q] = v0[q]; wq[4 + q] = v1[q]; }
    } else {
      const u16* W = (const u16*)Wq;
      union { uint4 v; u16 w[8]; } tv __attribute__((aligned(16)));
      tv.v = *(const uint4*)(W + base + e0);
#pragma unroll
      for (int q = 0; q < 8; ++q) wq[q] = b2f(tv.w[q]);
    }
#pragma unroll
    for (int e = 0; e < 8; ++e) {
      float w = wq[e];
      v4f k0 = *(const v4f*)&ks2[e0 + e][sb];
      v4f k1 = *(const v4f*)&ks2[e0 + e][sb + 4];
      a0 += w * k0;
      a1 += w * k1;
    }
  }
#pragma unroll
  for (int r = 0; r < 4; ++r) {
    Mt[(size_t)(h * 32 + sb + r) * 1024 + d]     = f2b(a0[r]);
    Mt[(size_t)(h * 32 + sb + 4 + r) * 1024 + d] = f2b(a1[r]);
  }
  if (dg == 0 && t < 32) {
    float a = 0.f;
    for (int e = 0; e < 64; ++e) a += ldin(bq, h * 64 + e, f32) * ks2[e][t];
    bias_s[h * 32 + t] = a;
  }
}

// ---------------- prep: N2t[h][j][r*32+s] = sum_d V[s, h*64+d] * Wo[r*64+d, j] ----
__global__ void kernel_N2(const float* __restrict__ Vf, const void* __restrict__ Wo,
                          u16* __restrict__ N2t, const int* __restrict__ flag) {
  const int f32 = *flag;
  int blk = blockIdx.x;             // 1024 blocks: h(16) x r(16) x jb(4)
  int h = blk >> 6, r = (blk >> 2) & 15, jb = blk & 3;
  int tid = threadIdx.x;
  int j = jb * 256 + tid;
  __shared__ float vsl[2048];       // V[s=0..31][d=0..63] for this h
  for (int i = tid; i < 2048; i += 256) {
    int s = i >> 6, d = i & 63;
    vsl[i] = Vf[(size_t)s * 1024 + h * 64 + d];
  }
  __syncthreads();
  float acc[32];
#pragma unroll
  for (int s = 0; s < 32; ++s) acc[s] = 0.f;
  for (int d = 0; d < 64; ++d) {
    float w = ldin(Wo, (size_t)(r * 64 + d) * 1024 + j, f32);
#pragma unroll
    for (int s = 0; s < 32; ++s) acc[s] += vsl[s * 64 + d] * w;
  }
  union { u16 o[32]; uint4 v[4]; } ou __attribute__((aligned(16)));
#pragma unroll
  for (int s = 0; s < 32; ++s) ou.o[s] = f2b(acc[s]);
  uint4* dst = (uint4*)(N2t + ((size_t)(h * 1024 + j)) * 512 + r * 32);
#pragma unroll
  for (int i = 0; i < 4; ++i) dst[i] = ou.v[i];
}

// ---------------- prep: bo -> fp32 ----------------
__global__ void kernel_bo(const void* __restrict__ bo, float* __restrict__ bo_f,
                          const int* __restrict__ flag) {
  const int f32 = *flag;
  int i = blockIdx.x * 256 + threadIdx.x;
  if (i < 1024) bo_f[i] = ldin(bo, i, f32);
}

// ---------------- GEMM1: Z2 = query @ Mt^T + bias_s, written permuted -------------
// C[rw][col] (rw in [0,32768), col=hs in [0,512)) -> Z2[h][rw>>4][(rw&15)*32 + s]
__global__ void gemm_scores(const void* __restrict__ A, const u16* __restrict__ B,
                            const float* __restrict__ bias, u16* __restrict__ Z2,
                            const int* __restrict__ flag) {
  const int f32 = *flag;
  const int K = 1024;
  __shared__ u16 As[128 * LDSW] __attribute__((aligned(16)));
  __shared__ u16 Bs[128 * LDSW] __attribute__((aligned(16)));
  const int tid = threadIdx.x;
  const int wave = tid >> 6;
  const int lane = tid & 63;
  const int quad = lane >> 4;
  const int l16 = lane & 15;
  const int m0 = blockIdx.y * 128;
  const int n0 = blockIdx.x * 128;
  const int wm = (wave >> 1) * 64;
  const int wn = (wave & 1) * 64;

  v4f acc[4][4] = {};

  const int idx0 = tid, idx1 = 256 + tid;
  const int r0 = idx0 >> 2, c0 = (idx0 & 3) * 8;
  const int r1 = idx1 >> 2, c1 = (idx1 & 3) * 8;
  const u16* Bb = B + (size_t)n0 * K;

  for (int k0 = 0; k0 < K; k0 += 32) {
    size_t offA0 = (size_t)(m0 + r0) * K + k0 + c0;
    size_t offA1 = (size_t)(m0 + r1) * K + k0 + c1;
    if (!f32) {
      *(uint4*)&As[r0 * LDSW + c0] = *(const uint4*)((const u16*)A + offA0);
      *(uint4*)&As[r1 * LDSW + c1] = *(const uint4*)((const u16*)A + offA1);
    } else {
      const float* fA = (const float*)A;
      // 32B-aligned offsets (k0%32==0, c0%8==0) -> vector loads
      v4f a0 = *(const v4f*)(fA + offA0);
      v4f a1 = *(const v4f*)(fA + offA0 + 4);
      v4f a2 = *(const v4f*)(fA + offA1);
      v4f a3 = *(const v4f*)(fA + offA1 + 4);
      union { uint4 v; u16 w[8]; } t0 __attribute__((aligned(16)));
      union { uint4 v; u16 w[8]; } t1 __attribute__((aligned(16)));
#pragma unroll
      for (int e = 0; e < 4; ++e) { t0.w[e] = f2b(a0[e]); t0.w[e + 4] = f2b(a1[e]); }
#pragma unroll
      for (int e = 0; e < 4; ++e) { t1.w[e] = f2b(a2[e]); t1.w[e + 4] = f2b(a3[e]); }
      *(uint4*)&As[r0 * LDSW + c0] = t0.v;
      *(uint4*)&As[r1 * LDSW + c1] = t1.v;
    }
    *(uint4*)&Bs[r0 * LDSW + c0] = *(const uint4*)(Bb + (size_t)r0 * K + k0 + c0);
    *(uint4*)&Bs[r1 * LDSW + c1] = *(const uint4*)(Bb + (size_t)r1 * K + k0 + c1);
    __syncthreads();
    short8 af[4], bf[4];
#pragma unroll
    for (int i = 0; i < 4; ++i)
      af[i] = *(const short8*)&As[(wm + i * 16 + l16) * LDSW + quad * 8];
#pragma unroll
    for (int i = 0; i < 4; ++i)
      bf[i] = *(const short8*)&Bs[(wn + i * 16 + l16) * LDSW + quad * 8];
#pragma unroll
    for (int mi = 0; mi < 4; ++mi)
#pragma unroll
      for (int ni = 0; ni < 4; ++ni)
        acc[mi][ni] = __builtin_amdgcn_mfma_f32_16x16x32_bf16(af[mi], bf[ni], acc[mi][ni], 0, 0, 0);
    __syncthreads();
  }

#pragma unroll
  for (int ni = 0; ni < 4; ++ni) {
    const int col = n0 + wn + ni * 16 + l16;
    const float bcol = bias[col];
    const int h = col >> 5, s = col & 31;
#pragma unroll
    for (int mi = 0; mi < 4; ++mi) {
      const int rbase = m0 + wm + mi * 16 + quad * 4;
#pragma unroll
      for (int rr = 0; rr < 4; ++rr) {
        const int rw = rbase + rr;
        const size_t addr = (size_t)h * 1048576 + (size_t)(rw >> 4) * 512 + (rw & 15) * 32 + s;
        Z2[addr] = f2b(acc[mi][ni][rr] + bcol);
      }
    }
  }
}

// ---------------- sparsemax over groups of 32, in place on Z2 (bf16) --------------
__global__ void sparsemax_k(u16* __restrict__ Z) {
  int t = blockIdx.x * 256 + threadIdx.x;   // 524288 groups of 32
  u16* zp = Z + (size_t)t * 32;
  union { uint4 v[4]; u16 w[32]; } raw __attribute__((aligned(16)));
  const uint4* rp4 = (const uint4*)zp;
#pragma unroll
  for (int i = 0; i < 4; ++i) raw.v[i] = rp4[i];
  float z[32], zs[32];
#pragma unroll
  for (int i = 0; i < 32; ++i) { z[i] = b2f(raw.w[i]); zs[i] = z[i]; }
#pragma unroll
  for (int kk = 2; kk <= 32; kk <<= 1) {
#pragma unroll
    for (int j = kk >> 1; j > 0; j >>= 1) {
#pragma unroll
      for (int i = 0; i < 32; ++i) {
        int ij = i ^ j;
        if (ij > i) {
          bool up = ((i & kk) == 0);
          float a = zs[i], b = zs[ij];
          float hi = fmaxf(a, b), lo = fminf(a, b);
          zs[i]  = up ? hi : lo;
          zs[ij] = up ? lo : hi;
        }
      }
    }
  }
  float cum = 0.f, cumsel = 0.f;
  int ksup = 1;
#pragma unroll
  for (int i = 0; i < 32; ++i) {
    cum += zs[i];
    if (1.f + (float)(i + 1) * zs[i] > cum) { ksup = i + 1; cumsel = cum; }
  }
  float tau = (cumsel - 1.f) / (float)ksup;
  union { u16 o[32]; uint4 v[4]; } ou __attribute__((aligned(16)));
#pragma unroll
  for (int i = 0; i < 32; ++i) ou.o[i] = f2b(fmaxf(z[i] - tau, 0.f));
  uint4* op = (uint4*)zp;
#pragma unroll
  for (int i = 0; i < 4; ++i) op[i] = ou.v[i];
}

// ---------------- GEMM2 (batched over h): out_h = A_sp_h @ N2t_h^T + bo -----------
__global__ void gemm_out(const u16* __restrict__ Z2, const u16* __restrict__ N2t,
                         const float* __restrict__ bias, void* __restrict__ out,
                         const int* __restrict__ flag) {
  const int f32 = *flag;
  const int K = 512;
  const int h = blockIdx.z;
  __shared__ u16 As[128 * LDSW] __attribute__((aligned(16)));
  __shared__ u16 Bs[128 * LDSW] __attribute__((aligned(16)));
  const int tid = threadIdx.x;
  const int wave = tid >> 6;
  const int lane = tid & 63;
  const int quad = lane >> 4;
  const int l16 = lane & 15;
  const int m0 = blockIdx.y * 128;
  const int n0 = blockIdx.x * 128;
  const int wm = (wave >> 1) * 64;
  const int wn = (wave & 1) * 64;

  v4f acc[4][4] = {};

  const u16* Ab = Z2 + (size_t)h * 2048 * 512 + (size_t)m0 * K;
  const u16* Bb = N2t + (size_t)h * 1024 * 512 + (size_t)n0 * K;
  const int idx0 = tid, idx1 = 256 + tid;
  const int r0 = idx0 >> 2, c0 = (idx0 & 3) * 8;
  const int r1 = idx1 >> 2, c1 = (idx1 & 3) * 8;

  for (int k0 = 0; k0 < K; k0 += 32) {
    *(uint4*)&As[r0 * LDSW + c0] = *(const uint4*)(Ab + (size_t)r0 * K + k0 + c0);
    *(uint4*)&As[r1 * LDSW + c1] = *(const uint4*)(Ab + (size_t)r1 * K + k0 + c1);
    *(uint4*)&Bs[r0 * LDSW + c0] = *(const uint4*)(Bb + (size_t)r0 * K + k0 + c0);
    *(uint4*)&Bs[r1 * LDSW + c1] = *(const uint4*)(Bb + (size_t)r1 * K + k0 + c1);
    __syncthreads();
    short8 af[4], bf[4];
#pragma unroll
    for (int i = 0; i < 4; ++i)
      af[i] = *(const short8*)&As[(wm + i * 16 + l16) * LDSW + quad * 8];
#pragma unroll
    for (int i = 0; i < 4; ++i)
      bf[i] = *(const short8*)&Bs[(wn + i * 16 + l16) * LDSW + quad * 8];
#pragma unroll
    for (int mi = 0; mi < 4; ++mi)
#pragma unroll
      for (int ni = 0; ni < 4; ++ni)
        acc[mi][ni] = __builtin_amdgcn_mfma_f32_16x16x32_bf16(af[mi], bf[ni], acc[mi][ni], 0, 0, 0);
    __syncthreads();
  }

  float bv4[4];
#pragma unroll
  for (int ni = 0; ni < 4; ++ni) bv4[ni] = bias[n0 + wn + ni * 16 + l16];
#pragma unroll
  for (int mi = 0; mi < 4; ++mi) {
    const int rl = m0 + wm + mi * 16 + quad * 4;
#pragma unroll
    for (int rr = 0; rr < 4; ++rr) {
      const int rlr = rl + rr;
      const int orow = (rlr >> 8) * 4096 + h * 256 + (rlr & 255);
#pragma unroll
      for (int ni = 0; ni < 4; ++ni) {
        const int col = n0 + wn + ni * 16 + l16;
        const float v = acc[mi][ni][rr] + bv4[ni];
        const size_t oi = (size_t)orow * 1024 + col;
        if (f32) ((float*)out)[oi] = v;
        else     ((u16*)out)[oi] = f2b(v);
      }
    }
  }
}

// ---------------- ws-light fused fallback ----------------
__global__ void __launch_bounds__(256) fused_fallback(
    const void* __restrict__ query, const u16* __restrict__ Mt,
    const float* __restrict__ bias_s, const u16* __restrict__ N2t,
    const float* __restrict__ bo_f, void* __restrict__ out,
    const int* __restrict__ flag) {
  const int f32 = *flag;
  __shared__ float sc[256 * 32];
  __shared__ u16 qch[256 * 72];
  __shared__ u16 mh[32 * 64];
  const int t = threadIdx.x;
  const int bb = blockIdx.x;              // 128 blocks: b(8) x atile(16)
  const int b = bb >> 4, atile = bb & 15;
  const int l0 = atile * 256;
  const size_t qbase = ((size_t)b * 4096 + l0) * 1024;

  for (int h = 0; h < 16; ++h) {
    float acc32[32];
#pragma unroll
    for (int s = 0; s < 32; ++s) acc32[s] = bias_s[h * 32 + s];
    for (int d0 = 0; d0 < 1024; d0 += 64) {
      __syncthreads();
#pragma unroll
      for (int i = 0; i < 8; ++i) {
        int f4 = t + i * 256;
        int row = f4 >> 3, c8 = f4 & 7;
        size_t off = qbase + (size_t)row * 1024 + d0 + c8 * 8;
        if (!f32) {
          *(uint4*)&qch[row * 72 + c8 * 8] = *(const uint4*)((const u16*)query + off);
        } else {
          union { uint4 v; u16 w[8]; } tq __attribute__((aligned(16)));
#pragma unroll
          for (int e = 0; e < 8; ++e) tq.w[e] = f2b(((const float*)query)[off + e]);
          *(uint4*)&qch[row * 72 + c8 * 8] = tq.v;
        }
      }
      { int row = t >> 3, c8 = t & 7;
        *(uint4*)&mh[row * 64 + c8 * 8] =
            *(const uint4*)(Mt + (size_t)(h * 32 + row) * 1024 + d0 + c8 * 8); }
      __syncthreads();
      float qrow[64];
#pragma unroll
      for (int c = 0; c < 64; ++c) qrow[c] = b2f(qch[t * 72 + c]);
#pragma unroll 4
      for (int s = 0; s < 32; ++s) {
        float a = 0.f;
#pragma unroll
        for (int c = 0; c < 64; ++c) a += qrow[c] * b2f(mh[s * 64 + c]);
        acc32[s] += a;
      }
    }
    float zs[32];
#pragma unroll
    for (int i = 0; i < 32; ++i) zs[i] = acc32[i];
#pragma unroll
    for (int kk = 2; kk <= 32; kk <<= 1) {
#pragma unroll
      for (int j = kk >> 1; j > 0; j >>= 1) {
#pragma unroll
        for (int i = 0; i < 32; ++i) {
          int ij = i ^ j;
          if (ij > i) {
            bool up = ((i & kk) == 0);
            float a = zs[i], bq_ = zs[ij];
            float hi = fmaxf(a, bq_), lo = fminf(a, bq_);
            zs[i]  = up ? hi : lo;
            zs[ij] = up ? lo : hi;
          }
        }
      }
    }
    float cum = 0.f, cumsel = 0.f;
    int ksup = 1;
#pragma unroll
    for (int i = 0; i < 32; ++i) {
      cum += zs[i];
      if (1.f + (float)(i + 1) * zs[i] > cum) { ksup = i + 1; cumsel = cum; }
    }
    float tau = (cumsel - 1.f) / (float)ksup;
#pragma unroll
    for (int s = 0; s < 32; ++s) sc[t * 32 + s] = fmaxf(acc32[s] - tau, 0.f);
    __syncthreads();
    for (int jj = 0; jj < 4; ++jj) {
      int j = t + jj * 256;
      const u16* nrow = N2t + ((size_t)h * 1024 + j) * 512;
      float acc16[16];
#pragma unroll
      for (int a = 0; a < 16; ++a) acc16[a] = 0.f;
      for (int k0 = 0; k0 < 512; k0 += 8) {
        union { uint4 v; u16 w[8]; } nv __attribute__((aligned(16)));
        nv.v = *(const uint4*)(nrow + k0);
#pragma unroll
        for (int kk = 0; kk < 8; ++kk) {
          float nf = b2f(nv.w[kk]);
#pragma unroll
          for (int a = 0; a < 16; ++a) acc16[a] += sc[a * 512 + k0 + kk] * nf;
        }
      }
      float bj = bo_f[j];
#pragma unroll
      for (int a = 0; a < 16; ++a) {
        int orow = b * 4096 + h * 256 + atile * 16 + a;
        size_t oi = (size_t)orow * 1024 + j;
        float v = acc16[a] + bj;
        if (f32) ((float*)out)[oi] = v;
        else     ((u16*)out)[oi] = f2b(v);
      }
    }
    __syncthreads();
  }
}

__global__ void zero_out(void* __restrict__ out, int n, const int* __restrict__ flag) {
  const int f32 = *flag;
  int i = blockIdx.x * 256 + threadIdx.x;
  if (i < n) { if (f32) ((float*)out)[i] = 0.f; else ((u16*)out)[i] = 0; }
}

extern "C" void kernel_launch(void* const* d_in, const int* in_sizes, int n_in,
                              void* d_out, int out_size, void* d_ws, size_t ws_size,
                              hipStream_t stream) {
  const void* query = d_in[0];
  const void* kp    = d_in[1];
  const void* Wq    = d_in[2];
  const void* bq    = d_in[3];
  const void* Wk    = d_in[4];
  const void* bk    = d_in[5];
  const void* Wv    = d_in[6];
  const void* bv    = d_in[7];
  const void* Wo    = d_in[8];
  const void* bo    = d_in[9];

  char* ws = (char*)d_ws;
  int*   flag   = (int*)(ws);                      // 4 B @ 0
  float* Kf     = (float*)(ws + (64 << 10));       // 128 KB
  float* Vf     = (float*)(ws + (192 << 10));      // 128 KB
  float* bias_s = (float*)(ws + (320 << 10));      // 2 KB
  float* bo_f   = (float*)(ws + (324 << 10));      // 4 KB
  u16*   Mt     = (u16*)(ws + (1 << 20));          // 1 MB
  u16*   N2t    = (u16*)(ws + (2 << 20));          // 16 MB
  u16*   Z2     = (u16*)(ws + (18 << 20));         // 32 MB (fast path only)

  const size_t WS_FAST = (size_t)(18 << 20) + 33554432;   // 50 MB
  const size_t WS_FALL = (size_t)(18 << 20);              // 18 MB

  sniff_k<<<1, 256, 0, stream>>>(query, flag);

  if (ws_size >= WS_FAST) {
    // K = kp @ Wk + bk ; V = Kf @ Wv + bv   (split-K=8, fp32 atomic accumulate)
    kv_zero<<<128, 256, 0, stream>>>(Kf, Vf);
    gemm_skinny_atomic<<<dim3(128, 8), 256, 0, stream>>>(kp, Wk, bk, Kf, flag, 0);
    gemm_skinny_atomic<<<dim3(128, 8), 256, 0, stream>>>(Kf, Wv, bv, Vf, flag, 1);
    kernel_M2<<<256, 256, 0, stream>>>(Kf, Wq, bq, Mt, bias_s, flag);
    kernel_N2<<<1024, 256, 0, stream>>>(Vf, Wo, N2t, flag);
    kernel_bo<<<4, 256, 0, stream>>>(bo, bo_f, flag);
    gemm_scores<<<dim3(512 / 128, 32768 / 128), 256, 0, stream>>>(query, Mt, bias_s, Z2, flag);
    sparsemax_k<<<2048, 256, 0, stream>>>(Z2);
    gemm_out<<<dim3(1024 / 128, 2048 / 128, 16), 256, 0, stream>>>(Z2, N2t, bo_f, d_out, flag);
  } else if (ws_size >= WS_FALL) {
    kernel_K<<<128, 256, 0, stream>>>(kp, Wk, bk, Kf, flag);
    kernel_V<<<128, 256, 0, stream>>>(Kf, Wv, bv, Vf, flag);
    kernel_M2<<<256, 256, 0, stream>>>(Kf, Wq, bq, Mt, bias_s, flag);
    kernel_N2<<<1024, 256, 0, stream>>>(Vf, Wo, N2t, flag);
    kernel_bo<<<4, 256, 0, stream>>>(bo, bo_f, flag);
    fused_fallback<<<128, 256, 0, stream>>>(query, Mt, bias_s, N2t, bo_f, d_out, flag);
  } else {
    zero_out<<<(out_size + 255) / 256, 256, 0, stream>>>(d_out, out_size, flag);
  }
}

// Round 4
// 451.130 us; speedup vs baseline: 1.7413x; 1.0305x over previous
//
#include <hip/hip_runtime.h>

typedef unsigned short u16;
typedef __attribute__((ext_vector_type(8))) short short8;
typedef __attribute__((ext_vector_type(4))) float v4f;

__device__ __forceinline__ float b2f(u16 u) {
  union { unsigned int i; float f; } v; v.i = ((unsigned int)u) << 16; return v.f;
}
__device__ __forceinline__ u16 f2b(float f) {
  unsigned int x = __float_as_uint(f);
  x += 0x7fffu + ((x >> 16) & 1u);   // RNE
  return (u16)(x >> 16);
}
// dtype-flexible input load: f32 ? fp32 array : bf16(u16) array
__device__ __forceinline__ float ldin(const void* p, size_t i, int f32) {
  return f32 ? ((const float*)p)[i] : b2f(((const u16*)p)[i]);
}

// LDS row stride for u16 GEMM tiles (pad found perf-neutral; kept at 40)
#define LDSW 40

// ---------------- dtype sniff: bf16 vs fp32, from query's raw bits ----------------
__global__ void sniff_k(const void* __restrict__ q, int* __restrict__ flag) {
  __shared__ int cnt;
  if (threadIdx.x == 0) cnt = 0;
  __syncthreads();
  const u16* p = (const u16*)q;
  int w = 0;
  for (int i = threadIdx.x; i < 1024; i += 256) {
    u16 u = p[i];
    int e = (u >> 7) & 0xFF;
    if (u != 0 && u != 0x8000 && (e >= 0xC0 || e < 0x40)) w++;
  }
  atomicAdd(&cnt, w);
  __syncthreads();
  if (threadIdx.x == 0) *flag = (cnt >= 32) ? 1 : 0;   // wild bits => fp32
}

// ---------------- zero-init for atomic split-K outputs ----------------
__global__ void kv_zero(float* __restrict__ Kf, float* __restrict__ Vf) {
  int i = blockIdx.x * 256 + threadIdx.x;   // 32768
  Kf[i] = 0.f;
  Vf[i] = 0.f;
}

// ---------------- skinny 32x1024 GEMM, split-K=8 via fp32 atomics ----------------
__global__ void gemm_skinny_atomic(const void* __restrict__ A, const void* __restrict__ W,
                                   const void* __restrict__ bias, float* __restrict__ C,
                                   const int* __restrict__ flag, int a_f32_always) {
  const int f32 = *flag;
  const int af = a_f32_always ? 1 : f32;
  const int t = blockIdx.x * 256 + threadIdx.x;   // 0..32767
  const int kb = blockIdx.y;                      // 0..7
  const int s = t >> 10, j = t & 1023;
  const int d0 = kb * 128;
  float acc = 0.f;
#pragma unroll 16
  for (int d = d0; d < d0 + 128; ++d)
    acc += ldin(A, (size_t)s * 1024 + d, af) * ldin(W, (size_t)d * 1024 + j, f32);
  if (kb == 0) acc += ldin(bias, j, f32);
  atomicAdd(&C[t], acc);
}

// ---------------- prep (fallback path only): K = key_param @ Wk + bk --------------
__global__ void kernel_K(const void* __restrict__ kp, const void* __restrict__ Wk,
                         const void* __restrict__ bk, float* __restrict__ Kf,
                         const int* __restrict__ flag) {
  const int f32 = *flag;
  int t = blockIdx.x * 256 + threadIdx.x;   // 32768 = 32 s x 1024 j
  int s = t >> 10, j = t & 1023;
  float acc = 0.f;
#pragma unroll 8
  for (int d = 0; d < 1024; ++d)
    acc += ldin(kp, (size_t)s * 1024 + d, f32) * ldin(Wk, (size_t)d * 1024 + j, f32);
  Kf[t] = acc + ldin(bk, j, f32);
}

// ---------------- prep (fallback path only): V = K @ Wv + bv ----------------
__global__ void kernel_V(const float* __restrict__ Kf, const void* __restrict__ Wv,
                         const void* __restrict__ bv, float* __restrict__ Vf,
                         const int* __restrict__ flag) {
  const int f32 = *flag;
  int t = blockIdx.x * 256 + threadIdx.x;
  int s = t >> 10, j = t & 1023;
  const float* kr = Kf + (size_t)s * 1024;
  float acc = 0.f;
#pragma unroll 8
  for (int d = 0; d < 1024; ++d) acc += kr[d] * ldin(Wv, (size_t)d * 1024 + j, f32);
  Vf[t] = acc + ldin(bv, j, f32);
}

// ---------------- prep: Mt[hs][d] = (1/8) sum_e Wq[d, h*64+e] * K[s, h*64+e] ------
__global__ void __launch_bounds__(256) kernel_M2(
    const float* __restrict__ Kf, const void* __restrict__ Wq,
    const void* __restrict__ bq, u16* __restrict__ Mt,
    float* __restrict__ bias_s, const int* __restrict__ flag) {
  const int f32 = *flag;
  const int blk = blockIdx.x;
  const int h = blk >> 4, dg = blk & 15;
  const int t = threadIdx.x;
  const int d = dg * 64 + (t & 63);
  const int sb = (t >> 6) * 8;
  __shared__ float ks2[64][32];     // [e][s], scaled by 0.125
  for (int i = t; i < 2048; i += 256) {
    int s = i & 31, e = i >> 5;
    ks2[e][s] = Kf[(size_t)s * 1024 + h * 64 + e] * 0.125f;
  }
  __syncthreads();
  v4f a0 = {0.f, 0.f, 0.f, 0.f}, a1 = {0.f, 0.f, 0.f, 0.f};
  const size_t base = (size_t)d * 1024 + h * 64;
  for (int e0 = 0; e0 < 64; e0 += 8) {
    float wq[8];
    if (f32) {
      const float* W = (const float*)Wq;
      v4f v0 = *(const v4f*)(W + base + e0);
      v4f v1 = *(const v4f*)(W + base + e0 + 4);
#pragma unroll
      for (int q = 0; q < 4; ++q) { wq[q] = v0[q]; wq[4 + q] = v1[q]; }
    } else {
      const u16* W = (const u16*)Wq;
      union { uint4 v; u16 w[8]; } tv __attribute__((aligned(16)));
      tv.v = *(const uint4*)(W + base + e0);
#pragma unroll
      for (int q = 0; q < 8; ++q) wq[q] = b2f(tv.w[q]);
    }
#pragma unroll
    for (int e = 0; e < 8; ++e) {
      float w = wq[e];
      v4f k0 = *(const v4f*)&ks2[e0 + e][sb];
      v4f k1 = *(const v4f*)&ks2[e0 + e][sb + 4];
      a0 += w * k0;
      a1 += w * k1;
    }
  }
#pragma unroll
  for (int r = 0; r < 4; ++r) {
    Mt[(size_t)(h * 32 + sb + r) * 1024 + d]     = f2b(a0[r]);
    Mt[(size_t)(h * 32 + sb + 4 + r) * 1024 + d] = f2b(a1[r]);
  }
  if (dg == 0 && t < 32) {
    float a = 0.f;
    for (int e = 0; e < 64; ++e) a += ldin(bq, h * 64 + e, f32) * ks2[e][t];
    bias_s[h * 32 + t] = a;
  }
}

// ---------------- prep: N2t[h][j][r*32+s] = sum_d V[s, h*64+d] * Wo[r*64+d, j] ----
__global__ void kernel_N2(const float* __restrict__ Vf, const void* __restrict__ Wo,
                          u16* __restrict__ N2t, const int* __restrict__ flag) {
  const int f32 = *flag;
  int blk = blockIdx.x;             // 1024 blocks: h(16) x r(16) x jb(4)
  int h = blk >> 6, r = (blk >> 2) & 15, jb = blk & 3;
  int tid = threadIdx.x;
  int j = jb * 256 + tid;
  __shared__ float vsl[2048];       // V[s=0..31][d=0..63] for this h
  for (int i = tid; i < 2048; i += 256) {
    int s = i >> 6, d = i & 63;
    vsl[i] = Vf[(size_t)s * 1024 + h * 64 + d];
  }
  __syncthreads();
  float acc[32];
#pragma unroll
  for (int s = 0; s < 32; ++s) acc[s] = 0.f;
  for (int d = 0; d < 64; ++d) {
    float w = ldin(Wo, (size_t)(r * 64 + d) * 1024 + j, f32);
#pragma unroll
    for (int s = 0; s < 32; ++s) acc[s] += vsl[s * 64 + d] * w;
  }
  union { u16 o[32]; uint4 v[4]; } ou __attribute__((aligned(16)));
#pragma unroll
  for (int s = 0; s < 32; ++s) ou.o[s] = f2b(acc[s]);
  uint4* dst = (uint4*)(N2t + ((size_t)(h * 1024 + j)) * 512 + r * 32);
#pragma unroll
  for (int i = 0; i < 4; ++i) dst[i] = ou.v[i];
}

// ---------------- prep: bo -> fp32 ----------------
__global__ void kernel_bo(const void* __restrict__ bo, float* __restrict__ bo_f,
                          const int* __restrict__ flag) {
  const int f32 = *flag;
  int i = blockIdx.x * 256 + threadIdx.x;
  if (i < 1024) bo_f[i] = ldin(bo, i, f32);
}

// ---------------- GEMM1 (wide-N): Z2 = query @ Mt^T + bias_s, permuted ------------
// One block owns 128 rows x ALL 512 cols: query read exactly once.
// 256 blocks (=1/CU) x 512 thr (8 waves: 2m x 4n, wave-tile 64x128).
__global__ void __launch_bounds__(512, 1) gemm_scores_wide(
    const void* __restrict__ A, const u16* __restrict__ B,
    const float* __restrict__ bias, u16* __restrict__ Z2,
    const int* __restrict__ flag) {
  const int f32 = *flag;
  const int K = 1024;
  __shared__ u16 As[128 * LDSW] __attribute__((aligned(16)));
  __shared__ u16 Bs[512 * LDSW] __attribute__((aligned(16)));
  const int tid = threadIdx.x;
  const int wave = tid >> 6;
  const int lane = tid & 63;
  const int quad = lane >> 4;
  const int l16 = lane & 15;
  const int m0 = blockIdx.x * 128;
  const int wm = (wave >> 2) * 64;        // 0 or 64
  const int wn = (wave & 3) * 128;        // 0,128,256,384

  v4f acc[4][8] = {};

  const int ra = tid >> 2, ca = (tid & 3) * 8;   // A-stage: 1 uint4/thread

  for (int k0 = 0; k0 < K; k0 += 32) {
    // ---- stage A (128 x 32) ----
    size_t offA = (size_t)(m0 + ra) * K + k0 + ca;
    if (!f32) {
      *(uint4*)&As[ra * LDSW + ca] = *(const uint4*)((const u16*)A + offA);
    } else {
      const float* fA = (const float*)A;
      v4f a0 = *(const v4f*)(fA + offA);
      v4f a1 = *(const v4f*)(fA + offA + 4);
      union { uint4 v; u16 w[8]; } t0 __attribute__((aligned(16)));
#pragma unroll
      for (int e = 0; e < 4; ++e) { t0.w[e] = f2b(a0[e]); t0.w[e + 4] = f2b(a1[e]); }
      *(uint4*)&As[ra * LDSW + ca] = t0.v;
    }
    // ---- stage B (512 x 32): 4 uint4/thread ----
#pragma unroll
    for (int p = 0; p < 4; ++p) {
      int idx = tid + p * 512;
      int rb = idx >> 2, cb = (idx & 3) * 8;
      *(uint4*)&Bs[rb * LDSW + cb] = *(const uint4*)(B + (size_t)rb * K + k0 + cb);
    }
    __syncthreads();
    short8 af[4], bf[8];
#pragma unroll
    for (int i = 0; i < 4; ++i)
      af[i] = *(const short8*)&As[(wm + i * 16 + l16) * LDSW + quad * 8];
#pragma unroll
    for (int i = 0; i < 8; ++i)
      bf[i] = *(const short8*)&Bs[(wn + i * 16 + l16) * LDSW + quad * 8];
#pragma unroll
    for (int mi = 0; mi < 4; ++mi)
#pragma unroll
      for (int ni = 0; ni < 8; ++ni)
        acc[mi][ni] = __builtin_amdgcn_mfma_f32_16x16x32_bf16(af[mi], bf[ni], acc[mi][ni], 0, 0, 0);
    __syncthreads();
  }

#pragma unroll
  for (int ni = 0; ni < 8; ++ni) {
    const int col = wn + ni * 16 + l16;
    const float bcol = bias[col];
    const int h = col >> 5, s = col & 31;
#pragma unroll
    for (int mi = 0; mi < 4; ++mi) {
      const int rbase = m0 + wm + mi * 16 + quad * 4;
#pragma unroll
      for (int rr = 0; rr < 4; ++rr) {
        const int rw = rbase + rr;
        const size_t addr = (size_t)h * 1048576 + (size_t)(rw >> 4) * 512 + (rw & 15) * 32 + s;
        Z2[addr] = f2b(acc[mi][ni][rr] + bcol);
      }
    }
  }
}

// ---------------- sparsemax over groups of 32, in place on Z2 (bf16) --------------
__global__ void sparsemax_k(u16* __restrict__ Z) {
  int t = blockIdx.x * 256 + threadIdx.x;   // 524288 groups of 32
  u16* zp = Z + (size_t)t * 32;
  union { uint4 v[4]; u16 w[32]; } raw __attribute__((aligned(16)));
  const uint4* rp4 = (const uint4*)zp;
#pragma unroll
  for (int i = 0; i < 4; ++i) raw.v[i] = rp4[i];
  float z[32], zs[32];
#pragma unroll
  for (int i = 0; i < 32; ++i) { z[i] = b2f(raw.w[i]); zs[i] = z[i]; }
#pragma unroll
  for (int kk = 2; kk <= 32; kk <<= 1) {
#pragma unroll
    for (int j = kk >> 1; j > 0; j >>= 1) {
#pragma unroll
      for (int i = 0; i < 32; ++i) {
        int ij = i ^ j;
        if (ij > i) {
          bool up = ((i & kk) == 0);
          float a = zs[i], b = zs[ij];
          float hi = fmaxf(a, b), lo = fminf(a, b);
          zs[i]  = up ? hi : lo;
          zs[ij] = up ? lo : hi;
        }
      }
    }
  }
  float cum = 0.f, cumsel = 0.f;
  int ksup = 1;
#pragma unroll
  for (int i = 0; i < 32; ++i) {
    cum += zs[i];
    if (1.f + (float)(i + 1) * zs[i] > cum) { ksup = i + 1; cumsel = cum; }
  }
  float tau = (cumsel - 1.f) / (float)ksup;
  union { u16 o[32]; uint4 v[4]; } ou __attribute__((aligned(16)));
#pragma unroll
  for (int i = 0; i < 32; ++i) ou.o[i] = f2b(fmaxf(z[i] - tau, 0.f));
  uint4* op = (uint4*)zp;
#pragma unroll
  for (int i = 0; i < 4; ++i) op[i] = ou.v[i];
}

// ---------------- GEMM2 (wide-N, batched over h): out_h = A_sp_h @ N2t_h^T + bo ---
// grid (2 n-halves, 16 m-tiles, 16 h); 8 waves, wave-tile 64x128.
__global__ void __launch_bounds__(512, 1) gemm_out_wide(
    const u16* __restrict__ Z2, const u16* __restrict__ N2t,
    const float* __restrict__ bias, void* __restrict__ out,
    const int* __restrict__ flag) {
  const int f32 = *flag;
  const int K = 512;
  const int h = blockIdx.z;
  __shared__ u16 As[128 * LDSW] __attribute__((aligned(16)));
  __shared__ u16 Bs[512 * LDSW] __attribute__((aligned(16)));
  const int tid = threadIdx.x;
  const int wave = tid >> 6;
  const int lane = tid & 63;
  const int quad = lane >> 4;
  const int l16 = lane & 15;
  const int m0 = blockIdx.y * 128;
  const int n0 = blockIdx.x * 512;
  const int wm = (wave >> 2) * 64;
  const int wn = (wave & 3) * 128;

  v4f acc[4][8] = {};

  const u16* Ab = Z2 + (size_t)h * 2048 * 512 + (size_t)m0 * K;
  const u16* Bb = N2t + (size_t)h * 1024 * 512 + (size_t)n0 * K;
  const int ra = tid >> 2, ca = (tid & 3) * 8;

  for (int k0 = 0; k0 < K; k0 += 32) {
    *(uint4*)&As[ra * LDSW + ca] = *(const uint4*)(Ab + (size_t)ra * K + k0 + ca);
#pragma unroll
    for (int p = 0; p < 4; ++p) {
      int idx = tid + p * 512;
      int rb = idx >> 2, cb = (idx & 3) * 8;
      *(uint4*)&Bs[rb * LDSW + cb] = *(const uint4*)(Bb + (size_t)rb * K + k0 + cb);
    }
    __syncthreads();
    short8 af[4], bf[8];
#pragma unroll
    for (int i = 0; i < 4; ++i)
      af[i] = *(const short8*)&As[(wm + i * 16 + l16) * LDSW + quad * 8];
#pragma unroll
    for (int i = 0; i < 8; ++i)
      bf[i] = *(const short8*)&Bs[(wn + i * 16 + l16) * LDSW + quad * 8];
#pragma unroll
    for (int mi = 0; mi < 4; ++mi)
#pragma unroll
      for (int ni = 0; ni < 8; ++ni)
        acc[mi][ni] = __builtin_amdgcn_mfma_f32_16x16x32_bf16(af[mi], bf[ni], acc[mi][ni], 0, 0, 0);
    __syncthreads();
  }

  float bv8[8];
#pragma unroll
  for (int ni = 0; ni < 8; ++ni) bv8[ni] = bias[n0 + wn + ni * 16 + l16];
#pragma unroll
  for (int mi = 0; mi < 4; ++mi) {
    const int rl = m0 + wm + mi * 16 + quad * 4;
#pragma unroll
    for (int rr = 0; rr < 4; ++rr) {
      const int rlr = rl + rr;
      const int orow = (rlr >> 8) * 4096 + h * 256 + (rlr & 255);
#pragma unroll
      for (int ni = 0; ni < 8; ++ni) {
        const int col = n0 + wn + ni * 16 + l16;
        const float v = acc[mi][ni][rr] + bv8[ni];
        const size_t oi = (size_t)orow * 1024 + col;
        if (f32) ((float*)out)[oi] = v;
        else     ((u16*)out)[oi] = f2b(v);
      }
    }
  }
}

// ---------------- ws-light fused fallback ----------------
__global__ void __launch_bounds__(256) fused_fallback(
    const void* __restrict__ query, const u16* __restrict__ Mt,
    const float* __restrict__ bias_s, const u16* __restrict__ N2t,
    const float* __restrict__ bo_f, void* __restrict__ out,
    const int* __restrict__ flag) {
  const int f32 = *flag;
  __shared__ float sc[256 * 32];
  __shared__ u16 qch[256 * 72];
  __shared__ u16 mh[32 * 64];
  const int t = threadIdx.x;
  const int bb = blockIdx.x;              // 128 blocks: b(8) x atile(16)
  const int b = bb >> 4, atile = bb & 15;
  const int l0 = atile * 256;
  const size_t qbase = ((size_t)b * 4096 + l0) * 1024;

  for (int h = 0; h < 16; ++h) {
    float acc32[32];
#pragma unroll
    for (int s = 0; s < 32; ++s) acc32[s] = bias_s[h * 32 + s];
    for (int d0 = 0; d0 < 1024; d0 += 64) {
      __syncthreads();
#pragma unroll
      for (int i = 0; i < 8; ++i) {
        int f4 = t + i * 256;
        int row = f4 >> 3, c8 = f4 & 7;
        size_t off = qbase + (size_t)row * 1024 + d0 + c8 * 8;
        if (!f32) {
          *(uint4*)&qch[row * 72 + c8 * 8] = *(const uint4*)((const u16*)query + off);
        } else {
          union { uint4 v; u16 w[8]; } tq __attribute__((aligned(16)));
#pragma unroll
          for (int e = 0; e < 8; ++e) tq.w[e] = f2b(((const float*)query)[off + e]);
          *(uint4*)&qch[row * 72 + c8 * 8] = tq.v;
        }
      }
      { int row = t >> 3, c8 = t & 7;
        *(uint4*)&mh[row * 64 + c8 * 8] =
            *(const uint4*)(Mt + (size_t)(h * 32 + row) * 1024 + d0 + c8 * 8); }
      __syncthreads();
      float qrow[64];
#pragma unroll
      for (int c = 0; c < 64; ++c) qrow[c] = b2f(qch[t * 72 + c]);
#pragma unroll 4
      for (int s = 0; s < 32; ++s) {
        float a = 0.f;
#pragma unroll
        for (int c = 0; c < 64; ++c) a += qrow[c] * b2f(mh[s * 64 + c]);
        acc32[s] += a;
      }
    }
    float zs[32];
#pragma unroll
    for (int i = 0; i < 32; ++i) zs[i] = acc32[i];
#pragma unroll
    for (int kk = 2; kk <= 32; kk <<= 1) {
#pragma unroll
      for (int j = kk >> 1; j > 0; j >>= 1) {
#pragma unroll
        for (int i = 0; i < 32; ++i) {
          int ij = i ^ j;
          if (ij > i) {
            bool up = ((i & kk) == 0);
            float a = zs[i], bq_ = zs[ij];
            float hi = fmaxf(a, bq_), lo = fminf(a, bq_);
            zs[i]  = up ? hi : lo;
            zs[ij] = up ? lo : hi;
          }
        }
      }
    }
    float cum = 0.f, cumsel = 0.f;
    int ksup = 1;
#pragma unroll
    for (int i = 0; i < 32; ++i) {
      cum += zs[i];
      if (1.f + (float)(i + 1) * zs[i] > cum) { ksup = i + 1; cumsel = cum; }
    }
    float tau = (cumsel - 1.f) / (float)ksup;
#pragma unroll
    for (int s = 0; s < 32; ++s) sc[t * 32 + s] = fmaxf(acc32[s] - tau, 0.f);
    __syncthreads();
    for (int jj = 0; jj < 4; ++jj) {
      int j = t + jj * 256;
      const u16* nrow = N2t + ((size_t)h * 1024 + j) * 512;
      float acc16[16];
#pragma unroll
      for (int a = 0; a < 16; ++a) acc16[a] = 0.f;
      for (int k0 = 0; k0 < 512; k0 += 8) {
        union { uint4 v; u16 w[8]; } nv __attribute__((aligned(16)));
        nv.v = *(const uint4*)(nrow + k0);
#pragma unroll
        for (int kk = 0; kk < 8; ++kk) {
          float nf = b2f(nv.w[kk]);
#pragma unroll
          for (int a = 0; a < 16; ++a) acc16[a] += sc[a * 512 + k0 + kk] * nf;
        }
      }
      float bj = bo_f[j];
#pragma unroll
      for (int a = 0; a < 16; ++a) {
        int orow = b * 4096 + h * 256 + atile * 16 + a;
        size_t oi = (size_t)orow * 1024 + j;
        float v = acc16[a] + bj;
        if (f32) ((float*)out)[oi] = v;
        else     ((u16*)out)[oi] = f2b(v);
      }
    }
    __syncthreads();
  }
}

__global__ void zero_out(void* __restrict__ out, int n, const int* __restrict__ flag) {
  const int f32 = *flag;
  int i = blockIdx.x * 256 + threadIdx.x;
  if (i < n) { if (f32) ((float*)out)[i] = 0.f; else ((u16*)out)[i] = 0; }
}

extern "C" void kernel_launch(void* const* d_in, const int* in_sizes, int n_in,
                              void* d_out, int out_size, void* d_ws, size_t ws_size,
                              hipStream_t stream) {
  const void* query = d_in[0];
  const void* kp    = d_in[1];
  const void* Wq    = d_in[2];
  const void* bq    = d_in[3];
  const void* Wk    = d_in[4];
  const void* bk    = d_in[5];
  const void* Wv    = d_in[6];
  const void* bv    = d_in[7];
  const void* Wo    = d_in[8];
  const void* bo    = d_in[9];

  char* ws = (char*)d_ws;
  int*   flag   = (int*)(ws);                      // 4 B @ 0
  float* Kf     = (float*)(ws + (64 << 10));       // 128 KB
  float* Vf     = (float*)(ws + (192 << 10));      // 128 KB
  float* bias_s = (float*)(ws + (320 << 10));      // 2 KB
  float* bo_f   = (float*)(ws + (324 << 10));      // 4 KB
  u16*   Mt     = (u16*)(ws + (1 << 20));          // 1 MB
  u16*   N2t    = (u16*)(ws + (2 << 20));          // 16 MB
  u16*   Z2     = (u16*)(ws + (18 << 20));         // 32 MB (fast path only)

  const size_t WS_FAST = (size_t)(18 << 20) + 33554432;   // 50 MB
  const size_t WS_FALL = (size_t)(18 << 20);              // 18 MB

  sniff_k<<<1, 256, 0, stream>>>(query, flag);

  if (ws_size >= WS_FAST) {
    // K = kp @ Wk + bk ; V = Kf @ Wv + bv   (split-K=8, fp32 atomic accumulate)
    kv_zero<<<128, 256, 0, stream>>>(Kf, Vf);
    gemm_skinny_atomic<<<dim3(128, 8), 256, 0, stream>>>(kp, Wk, bk, Kf, flag, 0);
    gemm_skinny_atomic<<<dim3(128, 8), 256, 0, stream>>>(Kf, Wv, bv, Vf, flag, 1);
    kernel_M2<<<256, 256, 0, stream>>>(Kf, Wq, bq, Mt, bias_s, flag);
    kernel_N2<<<1024, 256, 0, stream>>>(Vf, Wo, N2t, flag);
    kernel_bo<<<4, 256, 0, stream>>>(bo, bo_f, flag);
    gemm_scores_wide<<<256, 512, 0, stream>>>(query, Mt, bias_s, Z2, flag);
    sparsemax_k<<<2048, 256, 0, stream>>>(Z2);
    gemm_out_wide<<<dim3(2, 16, 16), 512, 0, stream>>>(Z2, N2t, bo_f, d_out, flag);
  } else if (ws_size >= WS_FALL) {
    kernel_K<<<128, 256, 0, stream>>>(kp, Wk, bk, Kf, flag);
    kernel_V<<<128, 256, 0, stream>>>(Kf, Wv, bv, Vf, flag);
    kernel_M2<<<256, 256, 0, stream>>>(Kf, Wq, bq, Mt, bias_s, flag);
    kernel_N2<<<1024, 256, 0, stream>>>(Vf, Wo, N2t, flag);
    kernel_bo<<<4, 256, 0, stream>>>(bo, bo_f, flag);
    fused_fallback<<<128, 256, 0, stream>>>(query, Mt, bias_s, N2t, bo_f, d_out, flag);
  } else {
    zero_out<<<(out_size + 255) / 256, 256, 0, stream>>>(d_out, out_size, flag);
  }
}